// Round 11
// baseline (249.029 us; speedup 1.0000x reference)
//
#include <hip/hip_runtime.h>
#include <stdint.h>

typedef __bf16 bf16;
typedef __bf16 bf16x8 __attribute__((ext_vector_type(8)));
typedef float floatx4 __attribute__((ext_vector_type(4)));

#define S_LEN 2048
#define DM 1024
#define NH 16
#define DK 64
#define MTOT 4096  // B*S

// async 16B/lane global->LDS DMA; lane l's 16B lands at ldsbase + l*16.
__device__ __forceinline__ void gll16(const void* g, void* l) {
  __builtin_amdgcn_global_load_lds(
      (const __attribute__((address_space(1))) void*)g,
      (__attribute__((address_space(3))) void*)l, 16, 0, 0);
}

// ---------------------------------------------------------------------------
// fp32 -> bf16 convert: Wq,Wk,Wv (512 chunks each) + Xq,Xk (2048 chunks each).
// ---------------------------------------------------------------------------
__global__ __launch_bounds__(256) void cvt_kernel(
    const float* __restrict__ Wq, const float* __restrict__ Wk, const float* __restrict__ Wv,
    const float* __restrict__ Xq, const float* __restrict__ Xk,
    bf16* __restrict__ wqb, bf16* __restrict__ wkb, bf16* __restrict__ wvb,
    bf16* __restrict__ xqb, bf16* __restrict__ xkb)
{
  const int c = blockIdx.x;
  const float* src; bf16* dst; int off;
  if      (c < 512)  { src = Wq; dst = wqb; off = c; }
  else if (c < 1024) { src = Wk; dst = wkb; off = c - 512; }
  else if (c < 1536) { src = Wv; dst = wvb; off = c - 1024; }
  else if (c < 3584) { src = Xq; dst = xqb; off = c - 1536; }
  else               { src = Xk; dst = xkb; off = c - 3584; }
  const size_t base = (size_t)off * 2048 + threadIdx.x * 8;
  float4 a = *(const float4*)(src + base);
  float4 b = *(const float4*)(src + base + 4);
  bf16x8 h;
  h[0] = (bf16)a.x; h[1] = (bf16)a.y; h[2] = (bf16)a.z; h[3] = (bf16)a.w;
  h[4] = (bf16)b.x; h[5] = (bf16)b.y; h[6] = (bf16)b.z; h[7] = (bf16)b.w;
  *(bf16x8*)(dst + base) = h;
}

// ---------------------------------------------------------------------------
// Q/K projection GEMM: 128x128 tile, BK=64, all-bf16, dbuf + counted vmcnt.
// (validated rounds 1/2/6/7/9)
// ---------------------------------------------------------------------------
__global__ __launch_bounds__(256) void proj_qk_kernel(
    const bf16* __restrict__ xqb, const bf16* __restrict__ xkb,
    const bf16* __restrict__ wqb, const bf16* __restrict__ wkb,
    const float* __restrict__ bqp, const float* __restrict__ bkp,
    bf16* __restrict__ qb, bf16* __restrict__ kb)
{
  const int bid = blockIdx.x;
  const int xcd = bid & 7;
  const int slot = bid >> 3;            // 0..63
  const int m_blk = xcd * 4 + (slot & 3);
  const int n_blk = (slot >> 2) & 7;
  const int z = slot >> 5;              // 0 -> q, 1 -> k

  const bf16* X     = z ? xkb : xqb;
  const bf16* W     = z ? wkb : wqb;
  const float* bias = z ? bkp : bqp;

  const int m0 = m_blk * 128;
  const int n0 = n_blk * 128;
  const int tid = threadIdx.x;
  const int lane = tid & 63;
  const int wid = tid >> 6;
  const int wm = (wid & 1) * 64;
  const int wn = (wid >> 1) * 64;

  __shared__ bf16 As[2][128 * 64];   // 2 x 16KB
  __shared__ bf16 Bs[2][128 * 64];   // 2 x 16KB

  floatx4 acc[4][4];
  #pragma unroll
  for (int i = 0; i < 4; i++)
    #pragma unroll
    for (int j = 0; j < 4; j++) acc[i][j] = (floatx4){0.f, 0.f, 0.f, 0.f};

  const int mr = lane & 15;
  const int q4 = lane >> 4;
  const int r8_in = lane >> 3, cb8_ph = lane & 7;

  // stage one K-step (32KB: A 16KB + B 16KB; 8 gll16/thread)
  #define STAGE_QK(buf, kt)                                                   \
    {                                                                         \
      _Pragma("unroll")                                                       \
      for (int j = 0; j < 4; j++) {                                           \
        const int c = wid * 4 + j;                                            \
        const int row = c * 8 + r8_in;                                        \
        const int cb = cb8_ph ^ (row & 7);                                    \
        gll16(X + (size_t)(m0 + row) * DM + (kt) + cb * 8, &As[buf][c * 512]);\
      }                                                                       \
      _Pragma("unroll")                                                       \
      for (int j = 0; j < 4; j++) {                                           \
        const int c = wid * 4 + j;                                            \
        const int row = c * 8 + r8_in;                                        \
        const int cb = cb8_ph ^ (row & 7);                                    \
        gll16(W + (size_t)(n0 + row) * DM + (kt) + cb * 8, &Bs[buf][c * 512]);\
      }                                                                       \
    }

  STAGE_QK(0, 0);
  int cur = 0;
  for (int kt = 0; kt < DM; kt += 64) {
    if (kt + 64 < DM) {
      STAGE_QK(cur ^ 1, kt + 64);
      asm volatile("s_waitcnt vmcnt(8)" ::: "memory");   // buf[cur]'s 8 landed
    } else {
      asm volatile("s_waitcnt vmcnt(0)" ::: "memory");
    }
    __builtin_amdgcn_s_barrier();   // buf[cur] visible to all waves

    #pragma unroll
    for (int kk = 0; kk < 2; kk++) {
      bf16x8 af[4], bfr[4];
      #pragma unroll
      for (int mt = 0; mt < 4; mt++) {
        const int row = wm + mt * 16 + mr;
        const int cb = 4 * kk + q4;
        af[mt] = *(const bf16x8*)&As[cur][row * 64 + (cb ^ (row & 7)) * 8];
      }
      #pragma unroll
      for (int nt = 0; nt < 4; nt++) {
        const int row = wn + nt * 16 + mr;
        const int cb = 4 * kk + q4;
        bfr[nt] = *(const bf16x8*)&Bs[cur][row * 64 + (cb ^ (row & 7)) * 8];
      }
      #pragma unroll
      for (int mt = 0; mt < 4; mt++)
        #pragma unroll
        for (int nt = 0; nt < 4; nt++)
          acc[mt][nt] = __builtin_amdgcn_mfma_f32_16x16x32_bf16(af[mt], bfr[nt], acc[mt][nt], 0, 0, 0);
    }

    __builtin_amdgcn_s_barrier();   // all reads of buf[cur] done (WAR close)
    cur ^= 1;
  }
  #undef STAGE_QK

  const float qscale = (z == 0) ? 0.125f : 1.0f;   // exact pow2: no extra rounding
  bf16* dst = (z == 0) ? qb : kb;
  #pragma unroll
  for (int nt = 0; nt < 4; nt++) {
    const int gn = n0 + wn + nt * 16 + mr;
    const float bv = bias[gn];
    const int h = gn >> 6, d = gn & 63;
    #pragma unroll
    for (int mt = 0; mt < 4; mt++) {
      const int mbase = m0 + wm + mt * 16 + q4 * 4;
      #pragma unroll
      for (int r = 0; r < 4; r++) {
        const int gm = mbase + r;
        const int bi = gm >> 11, s = gm & 2047;
        const bf16 hv = (bf16)((acc[mt][nt][r] + bv) * qscale);
        dst[(((size_t)(bi * NH + h)) * S_LEN + s) * DK + d] = hv;
      }
    }
  }
}

// ---------------------------------------------------------------------------
// V projection GEMM: A = Xv fp32 (staged raw), B = wvb bf16. dbuf, vmcnt(12).
// (validated rounds 1/2/6/7/9)
// ---------------------------------------------------------------------------
__global__ __launch_bounds__(256) void proj_v_kernel(
    const float* __restrict__ Xv, const bf16* __restrict__ wvb,
    const float* __restrict__ bvp, bf16* __restrict__ vtb)
{
  const int bid = blockIdx.x;
  const int xcd = bid & 7;
  const int slot = bid >> 3;            // 0..31
  const int m_blk = xcd * 4 + (slot & 3);
  const int n_blk = slot >> 2;          // 0..7

  const int m0 = m_blk * 128;
  const int n0 = n_blk * 128;
  const int tid = threadIdx.x;
  const int lane = tid & 63;
  const int wid = tid >> 6;
  const int wm = (wid & 1) * 64;
  const int wn = (wid >> 1) * 64;

  __shared__ float Asf[2][128 * 64];   // 2 x 32KB
  __shared__ bf16  Bs[2][128 * 64];    // 2 x 16KB

  floatx4 acc[4][4];
  #pragma unroll
  for (int i = 0; i < 4; i++)
    #pragma unroll
    for (int j = 0; j < 4; j++) acc[i][j] = (floatx4){0.f, 0.f, 0.f, 0.f};

  const int mr = lane & 15;
  const int q4 = lane >> 4;
  const int r8_in = lane >> 3, cb8_ph = lane & 7;
  const int r4_in = lane >> 4, cb16_ph = lane & 15;

  #define STAGE_V(buf, kt)                                                     \
    {                                                                          \
      _Pragma("unroll")                                                        \
      for (int j = 0; j < 8; j++) {                                            \
        const int c = wid * 8 + j;                                             \
        const int row = c * 4 + r4_in;                                         \
        const int cb = cb16_ph ^ (row & 7);                                    \
        gll16(Xv + (size_t)(m0 + row) * DM + (kt) + cb * 4, &Asf[buf][c * 256]);\
      }                                                                        \
      _Pragma("unroll")                                                        \
      for (int j = 0; j < 4; j++) {                                            \
        const int c = wid * 4 + j;                                             \
        const int row = c * 8 + r8_in;                                         \
        const int cb = cb8_ph ^ (row & 7);                                     \
        gll16(wvb + (size_t)(n0 + row) * DM + (kt) + cb * 8, &Bs[buf][c * 512]);\
      }                                                                        \
    }

  STAGE_V(0, 0);
  int cur = 0;
  for (int kt = 0; kt < DM; kt += 64) {
    if (kt + 64 < DM) {
      STAGE_V(cur ^ 1, kt + 64);
      asm volatile("s_waitcnt vmcnt(12)" ::: "memory");  // buf[cur]'s 12 landed
    } else {
      asm volatile("s_waitcnt vmcnt(0)" ::: "memory");
    }
    __builtin_amdgcn_s_barrier();

    #pragma unroll
    for (int kk = 0; kk < 2; kk++) {
      bf16x8 af[4], bfr[4];
      #pragma unroll
      for (int mt = 0; mt < 4; mt++) {
        const int row = wm + mt * 16 + mr;
        const int cb0 = 8 * kk + 2 * q4;
        const float4 lo = *(const float4*)&Asf[cur][row * 64 + (cb0 ^ (row & 7)) * 4];
        const float4 hi = *(const float4*)&Asf[cur][row * 64 + ((cb0 + 1) ^ (row & 7)) * 4];
        bf16x8 a;
        a[0] = (bf16)lo.x; a[1] = (bf16)lo.y; a[2] = (bf16)lo.z; a[3] = (bf16)lo.w;
        a[4] = (bf16)hi.x; a[5] = (bf16)hi.y; a[6] = (bf16)hi.z; a[7] = (bf16)hi.w;
        af[mt] = a;
      }
      #pragma unroll
      for (int nt = 0; nt < 4; nt++) {
        const int row = wn + nt * 16 + mr;
        const int cb = 4 * kk + q4;
        bfr[nt] = *(const bf16x8*)&Bs[cur][row * 64 + (cb ^ (row & 7)) * 8];
      }
      #pragma unroll
      for (int mt = 0; mt < 4; mt++)
        #pragma unroll
        for (int nt = 0; nt < 4; nt++)
          acc[mt][nt] = __builtin_amdgcn_mfma_f32_16x16x32_bf16(af[mt], bfr[nt], acc[mt][nt], 0, 0, 0);
    }

    __builtin_amdgcn_s_barrier();
    cur ^= 1;
  }
  #undef STAGE_V

  #pragma unroll
  for (int nt = 0; nt < 4; nt++) {
    const int gn = n0 + wn + nt * 16 + mr;
    const float bv = bvp[gn];
    const int h = gn >> 6, d = gn & 63;
    #pragma unroll
    for (int mt = 0; mt < 4; mt++) {
      const int mbase = m0 + wm + mt * 16 + q4 * 4;
      #pragma unroll
      for (int r = 0; r < 4; r++) {
        const int gm = mbase + r;
        const int bi = gm >> 11, s = gm & 2047;
        vtb[(((size_t)(bi * NH + h)) * DK + d) * S_LEN + s] = (bf16)(acc[mt][nt][r] + bv);
      }
    }
  }
}

// ---------------------------------------------------------------------------
// Flash attention, no-max softmax, q-tile 128 (wave owns 32 q-rows).
// Ks/Vs dbuf gll16 + counted vmcnt (r7); Psc chunked [4][32][40] (r7);
// setprio on MFMA clusters (r9). EXACT round-9 version (245.6 us passing).
// ---------------------------------------------------------------------------
__global__ __launch_bounds__(256) void attn_kernel(
    const bf16* __restrict__ qb, const bf16* __restrict__ kb,
    const bf16* __restrict__ vtb, bf16* __restrict__ ob)
{
  const int bid = blockIdx.x;
  const int xcd = bid & 7;
  const int slot = bid >> 3;          // 0..63
  const int bh = xcd * 4 + (slot & 3);
  const int qt = slot >> 2;           // 0..15

  const int tid = threadIdx.x;
  const int lane = tid & 63;
  const int wid = tid >> 6;

  const bf16* qh = qb + (size_t)bh * S_LEN * DK;
  const bf16* kh = kb + (size_t)bh * S_LEN * DK;
  const bf16* vh = vtb + (size_t)bh * DK * S_LEN;

  __shared__ bf16 Ks[2][128 * 64];   // 2 x 16KB [key][8 cb], phys cb=cb^(row&7)
  __shared__ bf16 Vs[2][64 * 128];   // 2 x 16KB [d][16 cb],  phys cb=cb^(row&7)
  __shared__ bf16 Psc[4][32][40];    // per-wave 32-col P chunk (80B rows)

  const int mr = lane & 15;
  const int q4 = lane >> 4;

  bf16x8 aq[2][2];
  #pragma unroll
  for (int mt = 0; mt < 2; mt++)
    #pragma unroll
    for (int kk = 0; kk < 2; kk++)
      aq[mt][kk] = *(const bf16x8*)(qh + (size_t)(qt * 128 + wid * 32 + mt * 16 + mr) * DK + kk * 32 + q4 * 8);

  floatx4 acc_o[2][4];
  #pragma unroll
  for (int mt = 0; mt < 2; mt++)
    #pragma unroll
    for (int dt = 0; dt < 4; dt++) acc_o[mt][dt] = (floatx4){0.f, 0.f, 0.f, 0.f};
  float l_p[2][4] = {{0.f,0.f,0.f,0.f},{0.f,0.f,0.f,0.f}};

  const int r8_in = lane >> 3, cb8_ph = lane & 7;
  const int r4_in = lane >> 4, cb16_ph = lane & 15;

  #define STAGE_A(buf, s0)                                                    \
    {                                                                         \
      _Pragma("unroll")                                                       \
      for (int j = 0; j < 4; j++) {                                           \
        const int c = wid * 4 + j;                                            \
        const int row = c * 8 + r8_in;                                        \
        const int cb = cb8_ph ^ (row & 7);                                    \
        gll16(kh + (size_t)((s0) + row) * DK + cb * 8, &Ks[buf][c * 512]);    \
      }                                                                       \
      _Pragma("unroll")                                                       \
      for (int j = 0; j < 4; j++) {                                           \
        const int c = wid * 4 + j;                                            \
        const int row = c * 4 + r4_in;                                        \
        const int cb = cb16_ph ^ (row & 7);                                   \
        gll16(vh + (size_t)row * S_LEN + (s0) + cb * 8, &Vs[buf][c * 512]);   \
      }                                                                       \
    }

  STAGE_A(0, 0);
  int cur = 0;
  for (int it = 0; it < S_LEN / 128; it++) {
    if (it + 1 < S_LEN / 128) {
      STAGE_A(cur ^ 1, (it + 1) * 128);
      asm volatile("s_waitcnt vmcnt(8)" ::: "memory");   // buf[cur]'s 8 landed
    } else {
      asm volatile("s_waitcnt vmcnt(0)" ::: "memory");
    }
    __builtin_amdgcn_s_barrier();   // buf[cur] visible to all waves

    // QK^T
    floatx4 sc[2][8];
    #pragma unroll
    for (int mt = 0; mt < 2; mt++)
      #pragma unroll
      for (int i = 0; i < 8; i++) sc[mt][i] = (floatx4){0.f, 0.f, 0.f, 0.f};
    __builtin_amdgcn_s_setprio(1);
    #pragma unroll
    for (int kk = 0; kk < 2; kk++) {
      #pragma unroll
      for (int nt = 0; nt < 8; nt++) {
        const int row = nt * 16 + mr;
        const int cb = kk * 4 + q4;
        bf16x8 b = *(const bf16x8*)&Ks[cur][row * 64 + (cb ^ (row & 7)) * 8];
        #pragma unroll
        for (int mt = 0; mt < 2; mt++)
          sc[mt][nt] = __builtin_amdgcn_mfma_f32_16x16x32_bf16(aq[mt][kk], b, sc[mt][nt], 0, 0, 0);
      }
    }
    __builtin_amdgcn_s_setprio(0);

    // chunked softmax -> PV: one 32-col P chunk per kk2 (per-wave private)
    #pragma unroll
    for (int kk2 = 0; kk2 < 4; kk2++) {
      #pragma unroll
      for (int mt = 0; mt < 2; mt++)
        #pragma unroll
        for (int nt2 = 0; nt2 < 2; nt2++)
          #pragma unroll
          for (int r = 0; r < 4; r++) {
            const float pv = __expf(sc[mt][kk2 * 2 + nt2][r]);
            l_p[mt][r] += pv;
            Psc[wid][mt * 16 + q4 * 4 + r][nt2 * 16 + mr] = (bf16)pv;
          }
      bf16x8 ap[2];
      #pragma unroll
      for (int mt = 0; mt < 2; mt++)
        ap[mt] = *(const bf16x8*)&Psc[wid][mt * 16 + mr][q4 * 8];
      __builtin_amdgcn_s_setprio(1);
      #pragma unroll
      for (int dt = 0; dt < 4; dt++) {
        const int row = dt * 16 + mr;
        const int cb = kk2 * 4 + q4;
        bf16x8 b = *(const bf16x8*)&Vs[cur][row * 128 + (cb ^ (row & 7)) * 8];
        #pragma unroll
        for (int mt = 0; mt < 2; mt++)
          acc_o[mt][dt] = __builtin_amdgcn_mfma_f32_16x16x32_bf16(ap[mt], b, acc_o[mt][dt], 0, 0, 0);
      }
      __builtin_amdgcn_s_setprio(0);
    }

    __builtin_amdgcn_s_barrier();   // all reads of buf[cur] done (WAR close)
    cur ^= 1;
  }
  #undef STAGE_A

  const int bi = bh >> 4, h = bh & 15;
  #pragma unroll
  for (int mt = 0; mt < 2; mt++) {
    float inv[4];
    #pragma unroll
    for (int r = 0; r < 4; r++) {
      float v = l_p[mt][r];
      #pragma unroll
      for (int off = 1; off < 16; off <<= 1) v += __shfl_xor(v, off, 16);
      inv[r] = 1.0f / v;
    }
    #pragma unroll
    for (int dt = 0; dt < 4; dt++) {
      const int d = dt * 16 + mr;
      #pragma unroll
      for (int r = 0; r < 4; r++) {
        const int s = qt * 128 + wid * 32 + mt * 16 + q4 * 4 + r;
        ob[((size_t)(bi * S_LEN + s)) * DM + h * DK + d] = (bf16)(acc_o[mt][dt][r] * inv[r]);
      }
    }
  }
}

// ---------------------------------------------------------------------------
// Output projection: out[m,n] = sum_k AO[m,k]*Wo[n,k] + bo[n], fp32 out.
// THIS ROUND: 128x128 tile (proj_v's structure with A/B dtype roles swapped:
// A = ao bf16 staged via proj_qk's 4-chunk path, B = Wo fp32 staged via
// proj_v's 8-chunk fp32 path, convert at fragment load). dbuf + vmcnt(12).
// 256 blocks (32 m-blk x 8 n-blk), proj_v's XCD decode. acc 4x4/wave.
// ---------------------------------------------------------------------------
__global__ __launch_bounds__(256) void oproj_kernel(
    const bf16* __restrict__ X, const float* __restrict__ W,
    const float* __restrict__ bias, float* __restrict__ out)
{
  const int bid = blockIdx.x;
  const int xcd = bid & 7;
  const int slot = bid >> 3;            // 0..31
  const int m_blk = xcd * 4 + (slot & 3);
  const int n_blk = slot >> 2;          // 0..7

  const int m0 = m_blk * 128;
  const int n0 = n_blk * 128;
  const int tid = threadIdx.x;
  const int lane = tid & 63;
  const int wid = tid >> 6;
  const int wm = (wid & 1) * 64;
  const int wn = (wid >> 1) * 64;

  __shared__ bf16  As[2][128 * 64];    // 2 x 16KB (A bf16)
  __shared__ float Bsf[2][128 * 64];   // 2 x 32KB (B fp32)

  floatx4 acc[4][4];
  #pragma unroll
  for (int i = 0; i < 4; i++)
    #pragma unroll
    for (int j = 0; j < 4; j++) acc[i][j] = (floatx4){0.f, 0.f, 0.f, 0.f};

  const int mr = lane & 15;
  const int q4 = lane >> 4;
  const int r8_in = lane >> 3, cb8_ph = lane & 7;
  const int r4_in = lane >> 4, cb16_ph = lane & 15;

  #define STAGE_O(buf, kt)                                                     \
    {                                                                          \
      _Pragma("unroll")                                                        \
      for (int j = 0; j < 4; j++) {                                            \
        const int c = wid * 4 + j;                                             \
        const int row = c * 8 + r8_in;                                         \
        const int cb = cb8_ph ^ (row & 7);                                     \
        gll16(X + (size_t)(m0 + row) * DM + (kt) + cb * 8, &As[buf][c * 512]); \
      }                                                                        \
      _Pragma("unroll")                                                        \
      for (int j = 0; j < 8; j++) {                                            \
        const int c = wid * 8 + j;                                             \
        const int row = c * 4 + r4_in;                                         \
        const int cb = cb16_ph ^ (row & 7);                                    \
        gll16(W + (size_t)(n0 + row) * DM + (kt) + cb * 4, &Bsf[buf][c * 256]);\
      }                                                                        \
    }

  STAGE_O(0, 0);
  int cur = 0;
  for (int kt = 0; kt < DM; kt += 64) {
    if (kt + 64 < DM) {
      STAGE_O(cur ^ 1, kt + 64);
      asm volatile("s_waitcnt vmcnt(12)" ::: "memory");  // buf[cur]'s 12 landed
    } else {
      asm volatile("s_waitcnt vmcnt(0)" ::: "memory");
    }
    __builtin_amdgcn_s_barrier();

    #pragma unroll
    for (int kk = 0; kk < 2; kk++) {
      bf16x8 af[4], bfr[4];
      #pragma unroll
      for (int mt = 0; mt < 4; mt++) {
        const int row = wm + mt * 16 + mr;
        const int cb = 4 * kk + q4;
        af[mt] = *(const bf16x8*)&As[cur][row * 64 + (cb ^ (row & 7)) * 8];
      }
      #pragma unroll
      for (int nt = 0; nt < 4; nt++) {
        const int row = wn + nt * 16 + mr;
        const int cb0 = 8 * kk + 2 * q4;
        const float4 lo = *(const float4*)&Bsf[cur][row * 64 + (cb0 ^ (row & 7)) * 4];
        const float4 hi = *(const float4*)&Bsf[cur][row * 64 + ((cb0 + 1) ^ (row & 7)) * 4];
        bf16x8 b;
        b[0] = (bf16)lo.x; b[1] = (bf16)lo.y; b[2] = (bf16)lo.z; b[3] = (bf16)lo.w;
        b[4] = (bf16)hi.x; b[5] = (bf16)hi.y; b[6] = (bf16)hi.z; b[7] = (bf16)hi.w;
        bfr[nt] = b;
      }
      #pragma unroll
      for (int mt = 0; mt < 4; mt++)
        #pragma unroll
        for (int nt = 0; nt < 4; nt++)
          acc[mt][nt] = __builtin_amdgcn_mfma_f32_16x16x32_bf16(af[mt], bfr[nt], acc[mt][nt], 0, 0, 0);
    }

    __builtin_amdgcn_s_barrier();
    cur ^= 1;
  }
  #undef STAGE_O

  #pragma unroll
  for (int nt = 0; nt < 4; nt++) {
    const int gn = n0 + wn + nt * 16 + mr;
    const float bv = bias[gn];
    #pragma unroll
    for (int mt = 0; mt < 4; mt++) {
      const int mbase = m0 + wm + mt * 16 + q4 * 4;
      #pragma unroll
      for (int r = 0; r < 4; r++)
        out[(size_t)(mbase + r) * DM + gn] = acc[mt][nt][r] + bv;
    }
  }
}

// ---------------------------------------------------------------------------
extern "C" void kernel_launch(void* const* d_in, const int* in_sizes, int n_in,
                              void* d_out, int out_size, void* d_ws, size_t ws_size,
                              hipStream_t stream) {
  const float* Q  = (const float*)d_in[0];
  const float* K  = (const float*)d_in[1];
  const float* V  = (const float*)d_in[2];
  const float* Wq = (const float*)d_in[3];
  const float* bq = (const float*)d_in[4];
  const float* Wk = (const float*)d_in[5];
  const float* bk = (const float*)d_in[6];
  const float* Wv = (const float*)d_in[7];
  const float* bv = (const float*)d_in[8];
  const float* Wo = (const float*)d_in[9];
  const float* bo = (const float*)d_in[10];
  float* out = (float*)d_out;

  const size_t NE = (size_t)MTOT * DM;      // 4 Mi elems
  bf16* qb  = (bf16*)d_ws;                  // [B,H,S,Dk] (q pre-scaled by 1/8)
  bf16* kb  = qb + NE;
  bf16* vtb = kb + NE;                      // [B,H,Dk,S]
  bf16* ao  = vtb + NE;                     // [B*S, DM] attn out
  // bf16 weights aliased into ao (live only during proj; attn overwrites ao).
  bf16* wqb = ao;
  bf16* wkb = ao + (size_t)DM * DM;
  bf16* wvb = ao + 2 * (size_t)DM * DM;
  // bf16 Xq/Xk staged in d_out (dead until oproj writes the real output).
  bf16* xqb = (bf16*)d_out;
  bf16* xkb = xqb + NE;

  cvt_kernel<<<dim3(5632), 256, 0, stream>>>(Wq, Wk, Wv, Q, K, wqb, wkb, wvb, xqb, xkb);
  proj_qk_kernel<<<dim3(512), 256, 0, stream>>>(xqb, xkb, wqb, wkb, bq, bk, qb, kb);
  proj_v_kernel<<<dim3(256), 256, 0, stream>>>(V, wvb, bv, vtb);
  attn_kernel<<<dim3(512), 256, 0, stream>>>(qb, kb, vtb, ao);
  oproj_kernel<<<dim3(256), 256, 0, stream>>>(ao, Wo, bo, out);
}

// Round 12
// 248.191 us; speedup vs baseline: 1.0034x; 1.0034x over previous
//
#include <hip/hip_runtime.h>
#include <stdint.h>

typedef __bf16 bf16;
typedef __bf16 bf16x8 __attribute__((ext_vector_type(8)));
typedef float floatx4 __attribute__((ext_vector_type(4)));

#define S_LEN 2048
#define DM 1024
#define NH 16
#define DK 64
#define MTOT 4096  // B*S

// async 16B/lane global->LDS DMA; lane l's 16B lands at ldsbase + l*16.
__device__ __forceinline__ void gll16(const void* g, void* l) {
  __builtin_amdgcn_global_load_lds(
      (const __attribute__((address_space(1))) void*)g,
      (__attribute__((address_space(3))) void*)l, 16, 0, 0);
}

// ---------------------------------------------------------------------------
// fp32 -> bf16 convert: Wq,Wk,Wv (512 chunks each) + Xq,Xk (2048 chunks each).
// ---------------------------------------------------------------------------
__global__ __launch_bounds__(256) void cvt_kernel(
    const float* __restrict__ Wq, const float* __restrict__ Wk, const float* __restrict__ Wv,
    const float* __restrict__ Xq, const float* __restrict__ Xk,
    bf16* __restrict__ wqb, bf16* __restrict__ wkb, bf16* __restrict__ wvb,
    bf16* __restrict__ xqb, bf16* __restrict__ xkb)
{
  const int c = blockIdx.x;
  const float* src; bf16* dst; int off;
  if      (c < 512)  { src = Wq; dst = wqb; off = c; }
  else if (c < 1024) { src = Wk; dst = wkb; off = c - 512; }
  else if (c < 1536) { src = Wv; dst = wvb; off = c - 1024; }
  else if (c < 3584) { src = Xq; dst = xqb; off = c - 1536; }
  else               { src = Xk; dst = xkb; off = c - 3584; }
  const size_t base = (size_t)off * 2048 + threadIdx.x * 8;
  float4 a = *(const float4*)(src + base);
  float4 b = *(const float4*)(src + base + 4);
  bf16x8 h;
  h[0] = (bf16)a.x; h[1] = (bf16)a.y; h[2] = (bf16)a.z; h[3] = (bf16)a.w;
  h[4] = (bf16)b.x; h[5] = (bf16)b.y; h[6] = (bf16)b.z; h[7] = (bf16)b.w;
  *(bf16x8*)(dst + base) = h;
}

// ---------------------------------------------------------------------------
// Q/K projection GEMM: 128x128 tile, BK=64, all-bf16, dbuf + counted vmcnt.
// (validated rounds 1/2/6/7/9/11)
// ---------------------------------------------------------------------------
__global__ __launch_bounds__(256) void proj_qk_kernel(
    const bf16* __restrict__ xqb, const bf16* __restrict__ xkb,
    const bf16* __restrict__ wqb, const bf16* __restrict__ wkb,
    const float* __restrict__ bqp, const float* __restrict__ bkp,
    bf16* __restrict__ qb, bf16* __restrict__ kb)
{
  const int bid = blockIdx.x;
  const int xcd = bid & 7;
  const int slot = bid >> 3;            // 0..63
  const int m_blk = xcd * 4 + (slot & 3);
  const int n_blk = (slot >> 2) & 7;
  const int z = slot >> 5;              // 0 -> q, 1 -> k

  const bf16* X     = z ? xkb : xqb;
  const bf16* W     = z ? wkb : wqb;
  const float* bias = z ? bkp : bqp;

  const int m0 = m_blk * 128;
  const int n0 = n_blk * 128;
  const int tid = threadIdx.x;
  const int lane = tid & 63;
  const int wid = tid >> 6;
  const int wm = (wid & 1) * 64;
  const int wn = (wid >> 1) * 64;

  __shared__ bf16 As[2][128 * 64];   // 2 x 16KB
  __shared__ bf16 Bs[2][128 * 64];   // 2 x 16KB

  floatx4 acc[4][4];
  #pragma unroll
  for (int i = 0; i < 4; i++)
    #pragma unroll
    for (int j = 0; j < 4; j++) acc[i][j] = (floatx4){0.f, 0.f, 0.f, 0.f};

  const int mr = lane & 15;
  const int q4 = lane >> 4;
  const int r8_in = lane >> 3, cb8_ph = lane & 7;

  // stage one K-step (32KB: A 16KB + B 16KB; 8 gll16/thread)
  #define STAGE_QK(buf, kt)                                                   \
    {                                                                         \
      _Pragma("unroll")                                                       \
      for (int j = 0; j < 4; j++) {                                           \
        const int c = wid * 4 + j;                                            \
        const int row = c * 8 + r8_in;                                        \
        const int cb = cb8_ph ^ (row & 7);                                    \
        gll16(X + (size_t)(m0 + row) * DM + (kt) + cb * 8, &As[buf][c * 512]);\
      }                                                                       \
      _Pragma("unroll")                                                       \
      for (int j = 0; j < 4; j++) {                                           \
        const int c = wid * 4 + j;                                            \
        const int row = c * 8 + r8_in;                                        \
        const int cb = cb8_ph ^ (row & 7);                                    \
        gll16(W + (size_t)(n0 + row) * DM + (kt) + cb * 8, &Bs[buf][c * 512]);\
      }                                                                       \
    }

  STAGE_QK(0, 0);
  int cur = 0;
  for (int kt = 0; kt < DM; kt += 64) {
    if (kt + 64 < DM) {
      STAGE_QK(cur ^ 1, kt + 64);
      asm volatile("s_waitcnt vmcnt(8)" ::: "memory");   // buf[cur]'s 8 landed
    } else {
      asm volatile("s_waitcnt vmcnt(0)" ::: "memory");
    }
    __builtin_amdgcn_s_barrier();   // buf[cur] visible to all waves

    #pragma unroll
    for (int kk = 0; kk < 2; kk++) {
      bf16x8 af[4], bfr[4];
      #pragma unroll
      for (int mt = 0; mt < 4; mt++) {
        const int row = wm + mt * 16 + mr;
        const int cb = 4 * kk + q4;
        af[mt] = *(const bf16x8*)&As[cur][row * 64 + (cb ^ (row & 7)) * 8];
      }
      #pragma unroll
      for (int nt = 0; nt < 4; nt++) {
        const int row = wn + nt * 16 + mr;
        const int cb = 4 * kk + q4;
        bfr[nt] = *(const bf16x8*)&Bs[cur][row * 64 + (cb ^ (row & 7)) * 8];
      }
      #pragma unroll
      for (int mt = 0; mt < 4; mt++)
        #pragma unroll
        for (int nt = 0; nt < 4; nt++)
          acc[mt][nt] = __builtin_amdgcn_mfma_f32_16x16x32_bf16(af[mt], bfr[nt], acc[mt][nt], 0, 0, 0);
    }

    __builtin_amdgcn_s_barrier();   // all reads of buf[cur] done (WAR close)
    cur ^= 1;
  }
  #undef STAGE_QK

  const float qscale = (z == 0) ? 0.125f : 1.0f;   // exact pow2: no extra rounding
  bf16* dst = (z == 0) ? qb : kb;
  #pragma unroll
  for (int nt = 0; nt < 4; nt++) {
    const int gn = n0 + wn + nt * 16 + mr;
    const float bv = bias[gn];
    const int h = gn >> 6, d = gn & 63;
    #pragma unroll
    for (int mt = 0; mt < 4; mt++) {
      const int mbase = m0 + wm + mt * 16 + q4 * 4;
      #pragma unroll
      for (int r = 0; r < 4; r++) {
        const int gm = mbase + r;
        const int bi = gm >> 11, s = gm & 2047;
        const bf16 hv = (bf16)((acc[mt][nt][r] + bv) * qscale);
        dst[(((size_t)(bi * NH + h)) * S_LEN + s) * DK + d] = hv;
      }
    }
  }
}

// ---------------------------------------------------------------------------
// V projection GEMM: A = Xv fp32 (staged raw), B = wvb bf16. dbuf, vmcnt(12).
// (validated rounds 1/2/6/7/9/11)
// ---------------------------------------------------------------------------
__global__ __launch_bounds__(256) void proj_v_kernel(
    const float* __restrict__ Xv, const bf16* __restrict__ wvb,
    const float* __restrict__ bvp, bf16* __restrict__ vtb)
{
  const int bid = blockIdx.x;
  const int xcd = bid & 7;
  const int slot = bid >> 3;            // 0..31
  const int m_blk = xcd * 4 + (slot & 3);
  const int n_blk = slot >> 2;          // 0..7

  const int m0 = m_blk * 128;
  const int n0 = n_blk * 128;
  const int tid = threadIdx.x;
  const int lane = tid & 63;
  const int wid = tid >> 6;
  const int wm = (wid & 1) * 64;
  const int wn = (wid >> 1) * 64;

  __shared__ float Asf[2][128 * 64];   // 2 x 32KB
  __shared__ bf16  Bs[2][128 * 64];    // 2 x 16KB

  floatx4 acc[4][4];
  #pragma unroll
  for (int i = 0; i < 4; i++)
    #pragma unroll
    for (int j = 0; j < 4; j++) acc[i][j] = (floatx4){0.f, 0.f, 0.f, 0.f};

  const int mr = lane & 15;
  const int q4 = lane >> 4;
  const int r8_in = lane >> 3, cb8_ph = lane & 7;
  const int r4_in = lane >> 4, cb16_ph = lane & 15;

  #define STAGE_V(buf, kt)                                                     \
    {                                                                          \
      _Pragma("unroll")                                                        \
      for (int j = 0; j < 8; j++) {                                            \
        const int c = wid * 8 + j;                                             \
        const int row = c * 4 + r4_in;                                         \
        const int cb = cb16_ph ^ (row & 7);                                    \
        gll16(Xv + (size_t)(m0 + row) * DM + (kt) + cb * 4, &Asf[buf][c * 256]);\
      }                                                                        \
      _Pragma("unroll")                                                        \
      for (int j = 0; j < 4; j++) {                                            \
        const int c = wid * 4 + j;                                             \
        const int row = c * 8 + r8_in;                                         \
        const int cb = cb8_ph ^ (row & 7);                                     \
        gll16(wvb + (size_t)(n0 + row) * DM + (kt) + cb * 8, &Bs[buf][c * 512]);\
      }                                                                        \
    }

  STAGE_V(0, 0);
  int cur = 0;
  for (int kt = 0; kt < DM; kt += 64) {
    if (kt + 64 < DM) {
      STAGE_V(cur ^ 1, kt + 64);
      asm volatile("s_waitcnt vmcnt(12)" ::: "memory");  // buf[cur]'s 12 landed
    } else {
      asm volatile("s_waitcnt vmcnt(0)" ::: "memory");
    }
    __builtin_amdgcn_s_barrier();

    #pragma unroll
    for (int kk = 0; kk < 2; kk++) {
      bf16x8 af[4], bfr[4];
      #pragma unroll
      for (int mt = 0; mt < 4; mt++) {
        const int row = wm + mt * 16 + mr;
        const int cb0 = 8 * kk + 2 * q4;
        const float4 lo = *(const float4*)&Asf[cur][row * 64 + (cb0 ^ (row & 7)) * 4];
        const float4 hi = *(const float4*)&Asf[cur][row * 64 + ((cb0 + 1) ^ (row & 7)) * 4];
        bf16x8 a;
        a[0] = (bf16)lo.x; a[1] = (bf16)lo.y; a[2] = (bf16)lo.z; a[3] = (bf16)lo.w;
        a[4] = (bf16)hi.x; a[5] = (bf16)hi.y; a[6] = (bf16)hi.z; a[7] = (bf16)hi.w;
        af[mt] = a;
      }
      #pragma unroll
      for (int nt = 0; nt < 4; nt++) {
        const int row = wn + nt * 16 + mr;
        const int cb = 4 * kk + q4;
        bfr[nt] = *(const bf16x8*)&Bs[cur][row * 64 + (cb ^ (row & 7)) * 8];
      }
      #pragma unroll
      for (int mt = 0; mt < 4; mt++)
        #pragma unroll
        for (int nt = 0; nt < 4; nt++)
          acc[mt][nt] = __builtin_amdgcn_mfma_f32_16x16x32_bf16(af[mt], bfr[nt], acc[mt][nt], 0, 0, 0);
    }

    __builtin_amdgcn_s_barrier();
    cur ^= 1;
  }
  #undef STAGE_V

  #pragma unroll
  for (int nt = 0; nt < 4; nt++) {
    const int gn = n0 + wn + nt * 16 + mr;
    const float bv = bvp[gn];
    const int h = gn >> 6, d = gn & 63;
    #pragma unroll
    for (int mt = 0; mt < 4; mt++) {
      const int mbase = m0 + wm + mt * 16 + q4 * 4;
      #pragma unroll
      for (int r = 0; r < 4; r++) {
        const int gm = mbase + r;
        const int bi = gm >> 11, s = gm & 2047;
        vtb[(((size_t)(bi * NH + h)) * DK + d) * S_LEN + s] = (bf16)(acc[mt][nt][r] + bv);
      }
    }
  }
}

// ---------------------------------------------------------------------------
// Flash attention, no-max softmax. THIS ROUND: QBLK=64, KVBLK=64 (halved
// tiles of the r9-validated structure; mt-dimension deleted, patterns
// verbatim). LDS 37,888B -> 4 blocks/CU; 1024 blocks -> 4 waves/SIMD (2x
// occupancy vs r9's 2). Stage = 4 gll16/thread -> vmcnt(4). 32 iterations.
// ---------------------------------------------------------------------------
__global__ __launch_bounds__(256, 4) void attn_kernel(
    const bf16* __restrict__ qb, const bf16* __restrict__ kb,
    const bf16* __restrict__ vtb, bf16* __restrict__ ob)
{
  const int bid = blockIdx.x;
  const int xcd = bid & 7;
  const int slot = bid >> 3;          // 0..127
  const int bh = xcd * 4 + (slot & 3);
  const int qt = slot >> 2;           // 0..31 (64-row q tiles)

  const int tid = threadIdx.x;
  const int lane = tid & 63;
  const int wid = tid >> 6;

  const bf16* qh = qb + (size_t)bh * S_LEN * DK;
  const bf16* kh = kb + (size_t)bh * S_LEN * DK;
  const bf16* vh = vtb + (size_t)bh * DK * S_LEN;

  __shared__ bf16 Ks[2][64 * 64];   // 2 x 8KB [key][8 cb], phys cb=cb^(key&7)
  __shared__ bf16 Vs[2][64 * 64];   // 2 x 8KB [d][8 cb],  phys cb=cb^(d&7)
  __shared__ bf16 Psc[4][16][40];   // per-wave 32-key P chunk (80B rows, 16B-aligned)

  const int mr = lane & 15;
  const int q4 = lane >> 4;

  // wave owns 16 q-rows: qt*64 + wid*16 + mr
  bf16x8 aq[2];
  #pragma unroll
  for (int kk = 0; kk < 2; kk++)
    aq[kk] = *(const bf16x8*)(qh + (size_t)(qt * 64 + wid * 16 + mr) * DK + kk * 32 + q4 * 8);

  floatx4 acc_o[4];
  #pragma unroll
  for (int dt = 0; dt < 4; dt++) acc_o[dt] = (floatx4){0.f, 0.f, 0.f, 0.f};
  float l_p[4] = {0.f, 0.f, 0.f, 0.f};

  const int r8_in = lane >> 3, cb8_ph = lane & 7;

  // stage one 64-key K/V tile (16KB total; 4 gll16/thread)
  #define STAGE_A(buf, s0)                                                    \
    {                                                                         \
      _Pragma("unroll")                                                       \
      for (int j = 0; j < 2; j++) {                                           \
        const int c = wid * 2 + j;                                            \
        const int row = c * 8 + r8_in;                                        \
        const int cb = cb8_ph ^ (row & 7);                                    \
        gll16(kh + (size_t)((s0) + row) * DK + cb * 8, &Ks[buf][c * 512]);    \
      }                                                                       \
      _Pragma("unroll")                                                       \
      for (int j = 0; j < 2; j++) {                                           \
        const int c = wid * 2 + j;                                            \
        const int d = c * 8 + r8_in;                                          \
        const int cb = cb8_ph ^ (d & 7);                                      \
        gll16(vh + (size_t)d * S_LEN + (s0) + cb * 8, &Vs[buf][c * 512]);     \
      }                                                                       \
    }

  STAGE_A(0, 0);
  int cur = 0;
  for (int it = 0; it < S_LEN / 64; it++) {
    if (it + 1 < S_LEN / 64) {
      STAGE_A(cur ^ 1, (it + 1) * 64);
      asm volatile("s_waitcnt vmcnt(4)" ::: "memory");   // buf[cur]'s 4 landed
    } else {
      asm volatile("s_waitcnt vmcnt(0)" ::: "memory");
    }
    __builtin_amdgcn_s_barrier();   // buf[cur] visible to all waves

    // QK^T: 64 keys -> sc[4]
    floatx4 sc[4];
    #pragma unroll
    for (int i = 0; i < 4; i++) sc[i] = (floatx4){0.f, 0.f, 0.f, 0.f};
    __builtin_amdgcn_s_setprio(1);
    #pragma unroll
    for (int kk = 0; kk < 2; kk++) {
      #pragma unroll
      for (int nt = 0; nt < 4; nt++) {
        const int row = nt * 16 + mr;
        const int cb = kk * 4 + q4;
        bf16x8 b = *(const bf16x8*)&Ks[cur][row * 64 + (cb ^ (row & 7)) * 8];
        sc[nt] = __builtin_amdgcn_mfma_f32_16x16x32_bf16(aq[kk], b, sc[nt], 0, 0, 0);
      }
    }
    __builtin_amdgcn_s_setprio(0);

    // chunked softmax -> PV: one 32-key chunk per kk2 (per-wave private)
    #pragma unroll
    for (int kk2 = 0; kk2 < 2; kk2++) {
      #pragma unroll
      for (int nt2 = 0; nt2 < 2; nt2++)
        #pragma unroll
        for (int r = 0; r < 4; r++) {
          const float pv = __expf(sc[kk2 * 2 + nt2][r]);
          l_p[r] += pv;
          Psc[wid][q4 * 4 + r][nt2 * 16 + mr] = (bf16)pv;
        }
      bf16x8 ap = *(const bf16x8*)&Psc[wid][mr][q4 * 8];
      __builtin_amdgcn_s_setprio(1);
      #pragma unroll
      for (int dt = 0; dt < 4; dt++) {
        const int row = dt * 16 + mr;
        const int cb = kk2 * 4 + q4;
        bf16x8 b = *(const bf16x8*)&Vs[cur][row * 64 + (cb ^ (row & 7)) * 8];
        acc_o[dt] = __builtin_amdgcn_mfma_f32_16x16x32_bf16(ap, b, acc_o[dt], 0, 0, 0);
      }
      __builtin_amdgcn_s_setprio(0);
    }

    __builtin_amdgcn_s_barrier();   // all reads of buf[cur] done (WAR close)
    cur ^= 1;
  }
  #undef STAGE_A

  const int bi = bh >> 4, h = bh & 15;
  float inv[4];
  #pragma unroll
  for (int r = 0; r < 4; r++) {
    float v = l_p[r];
    #pragma unroll
    for (int off = 1; off < 16; off <<= 1) v += __shfl_xor(v, off, 16);
    inv[r] = 1.0f / v;
  }
  #pragma unroll
  for (int dt = 0; dt < 4; dt++) {
    const int d = dt * 16 + mr;
    #pragma unroll
    for (int r = 0; r < 4; r++) {
      const int s = qt * 64 + wid * 16 + q4 * 4 + r;
      ob[((size_t)(bi * S_LEN + s)) * DM + h * DK + d] = (bf16)(acc_o[dt][r] * inv[r]);
    }
  }
}

// ---------------------------------------------------------------------------
// Output projection: out[m,n] = sum_k AO[m,k]*Wo[n,k] + bo[n], fp32 out.
// 128x64 tile, BK=64. dbuf + counted vmcnt (validated rounds 6/7/9 — the
// best-total r9 configuration, reverted from r11's neutral 128x128 variant).
// ---------------------------------------------------------------------------
__global__ __launch_bounds__(256) void oproj_kernel(
    const bf16* __restrict__ X, const float* __restrict__ W,
    const float* __restrict__ bias, float* __restrict__ out)
{
  const int bid = blockIdx.x;
  const int xcd = bid & 7;
  const int slot = bid >> 3;              // 0..63
  const int m0 = (xcd * 4 + (slot & 3)) * 128;
  const int n0 = (slot >> 2) * 64;        // 0..15 -> n0

  const int tid = threadIdx.x;
  const int lane = tid & 63;
  const int wid = tid >> 6;
  const int wm = wid * 32;

  __shared__ bf16  As[2][128 * 64];   // 2 x 16KB
  __shared__ float Bsf[2][64 * 64];   // 2 x 16KB

  floatx4 acc[2][4];
  #pragma unroll
  for (int i = 0; i < 2; i++)
    #pragma unroll
    for (int j = 0; j < 4; j++) acc[i][j] = (floatx4){0.f, 0.f, 0.f, 0.f};

  const int mr = lane & 15;
  const int q4 = lane >> 4;

  const int r8_in = lane >> 3, cb8_ph = lane & 7;
  const int r4_in = lane >> 4, cb16_ph = lane & 15;

  #define STAGE_O(buf, kt)                                                    \
    {                                                                         \
      _Pragma("unroll")                                                       \
      for (int j = 0; j < 4; j++) {                                           \
        const int c = wid * 4 + j;                                            \
        const int row = c * 8 + r8_in;                                        \
        const int cb = cb8_ph ^ (row & 7);                                    \
        gll16(X + (size_t)(m0 + row) * DM + (kt) + cb * 8, &As[buf][c * 512]);\
      }                                                                       \
      _Pragma("unroll")                                                       \
      for (int j = 0; j < 4; j++) {                                           \
        const int c = wid * 4 + j;                                            \
        const int row = c * 4 + r4_in;                                        \
        const int cb = cb16_ph ^ (row & 7);                                   \
        gll16(W + (size_t)(n0 + row) * DM + (kt) + cb * 4, &Bsf[buf][c * 256]);\
      }                                                                       \
    }

  STAGE_O(0, 0);
  int cur = 0;
  for (int kt = 0; kt < DM; kt += 64) {
    if (kt + 64 < DM) {
      STAGE_O(cur ^ 1, kt + 64);
      asm volatile("s_waitcnt vmcnt(8)" ::: "memory");   // buf[cur]'s 8 landed
    } else {
      asm volatile("s_waitcnt vmcnt(0)" ::: "memory");
    }
    __builtin_amdgcn_s_barrier();

    #pragma unroll
    for (int kk = 0; kk < 2; kk++) {
      bf16x8 af[2], bfr[4];
      #pragma unroll
      for (int mt = 0; mt < 2; mt++) {
        const int row = wm + mt * 16 + mr;
        const int cb = 4 * kk + q4;
        af[mt] = *(const bf16x8*)&As[cur][row * 64 + (cb ^ (row & 7)) * 8];
      }
      #pragma unroll
      for (int nt = 0; nt < 4; nt++) {
        const int row = nt * 16 + mr;
        const int cb0 = 8 * kk + 2 * q4;
        const float4 lo = *(const float4*)&Bsf[cur][row * 64 + (cb0 ^ (row & 7)) * 4];
        const float4 hi = *(const float4*)&Bsf[cur][row * 64 + ((cb0 + 1) ^ (row & 7)) * 4];
        bf16x8 b;
        b[0] = (bf16)lo.x; b[1] = (bf16)lo.y; b[2] = (bf16)lo.z; b[3] = (bf16)lo.w;
        b[4] = (bf16)hi.x; b[5] = (bf16)hi.y; b[6] = (bf16)hi.z; b[7] = (bf16)hi.w;
        bfr[nt] = b;
      }
      #pragma unroll
      for (int mt = 0; mt < 2; mt++)
        #pragma unroll
        for (int nt = 0; nt < 4; nt++)
          acc[mt][nt] = __builtin_amdgcn_mfma_f32_16x16x32_bf16(af[mt], bfr[nt], acc[mt][nt], 0, 0, 0);
    }

    __builtin_amdgcn_s_barrier();
    cur ^= 1;
  }
  #undef STAGE_O

  #pragma unroll
  for (int nt = 0; nt < 4; nt++) {
    const int gn = n0 + nt * 16 + mr;
    const float bv = bias[gn];
    #pragma unroll
    for (int mt = 0; mt < 2; mt++) {
      const int mbase = m0 + wm + mt * 16 + q4 * 4;
      #pragma unroll
      for (int r = 0; r < 4; r++)
        out[(size_t)(mbase + r) * DM + gn] = acc[mt][nt][r] + bv;
    }
  }
}

// ---------------------------------------------------------------------------
extern "C" void kernel_launch(void* const* d_in, const int* in_sizes, int n_in,
                              void* d_out, int out_size, void* d_ws, size_t ws_size,
                              hipStream_t stream) {
  const float* Q  = (const float*)d_in[0];
  const float* K  = (const float*)d_in[1];
  const float* V  = (const float*)d_in[2];
  const float* Wq = (const float*)d_in[3];
  const float* bq = (const float*)d_in[4];
  const float* Wk = (const float*)d_in[5];
  const float* bk = (const float*)d_in[6];
  const float* Wv = (const float*)d_in[7];
  const float* bv = (const float*)d_in[8];
  const float* Wo = (const float*)d_in[9];
  const float* bo = (const float*)d_in[10];
  float* out = (float*)d_out;

  const size_t NE = (size_t)MTOT * DM;      // 4 Mi elems
  bf16* qb  = (bf16*)d_ws;                  // [B,H,S,Dk] (q pre-scaled by 1/8)
  bf16* kb  = qb + NE;
  bf16* vtb = kb + NE;                      // [B,H,Dk,S]
  bf16* ao  = vtb + NE;                     // [B*S, DM] attn out
  // bf16 weights aliased into ao (live only during proj; attn overwrites ao).
  bf16* wqb = ao;
  bf16* wkb = ao + (size_t)DM * DM;
  bf16* wvb = ao + 2 * (size_t)DM * DM;
  // bf16 Xq/Xk staged in d_out (dead until oproj writes the real output).
  bf16* xqb = (bf16*)d_out;
  bf16* xkb = xqb + NE;

  cvt_kernel<<<dim3(5632), 256, 0, stream>>>(Wq, Wk, Wv, Q, K, wqb, wkb, wvb, xqb, xkb);
  proj_qk_kernel<<<dim3(512), 256, 0, stream>>>(xqb, xkb, wqb, wkb, bq, bk, qb, kb);
  proj_v_kernel<<<dim3(256), 256, 0, stream>>>(V, wvb, bv, vtb);
  attn_kernel<<<dim3(1024), 256, 0, stream>>>(qb, kb, vtb, ao);
  oproj_kernel<<<dim3(512), 256, 0, stream>>>(ao, Wo, bo, out);
}

// Round 13
// 244.566 us; speedup vs baseline: 1.0183x; 1.0148x over previous
//
#include <hip/hip_runtime.h>
#include <stdint.h>

typedef __bf16 bf16;
typedef __bf16 bf16x8 __attribute__((ext_vector_type(8)));
typedef float floatx4 __attribute__((ext_vector_type(4)));

#define S_LEN 2048
#define DM 1024
#define NH 16
#define DK 64
#define MTOT 4096  // B*S

// async 16B/lane global->LDS DMA; lane l's 16B lands at ldsbase + l*16.
__device__ __forceinline__ void gll16(const void* g, void* l) {
  __builtin_amdgcn_global_load_lds(
      (const __attribute__((address_space(1))) void*)g,
      (__attribute__((address_space(3))) void*)l, 16, 0, 0);
}

// 2^x via the native transcendental (log2e folded into q upstream, in fp32).
__device__ __forceinline__ float exp2_fast(float x) {
  float r; asm("v_exp_f32 %0, %1" : "=v"(r) : "v"(x)); return r;
}

// ---------------------------------------------------------------------------
// fp32 -> bf16 convert: Wq,Wk,Wv (512 chunks each) + Xq,Xk (2048 chunks each).
// ---------------------------------------------------------------------------
__global__ __launch_bounds__(256) void cvt_kernel(
    const float* __restrict__ Wq, const float* __restrict__ Wk, const float* __restrict__ Wv,
    const float* __restrict__ Xq, const float* __restrict__ Xk,
    bf16* __restrict__ wqb, bf16* __restrict__ wkb, bf16* __restrict__ wvb,
    bf16* __restrict__ xqb, bf16* __restrict__ xkb)
{
  const int c = blockIdx.x;
  const float* src; bf16* dst; int off;
  if      (c < 512)  { src = Wq; dst = wqb; off = c; }
  else if (c < 1024) { src = Wk; dst = wkb; off = c - 512; }
  else if (c < 1536) { src = Wv; dst = wvb; off = c - 1024; }
  else if (c < 3584) { src = Xq; dst = xqb; off = c - 1536; }
  else               { src = Xk; dst = xkb; off = c - 3584; }
  const size_t base = (size_t)off * 2048 + threadIdx.x * 8;
  float4 a = *(const float4*)(src + base);
  float4 b = *(const float4*)(src + base + 4);
  bf16x8 h;
  h[0] = (bf16)a.x; h[1] = (bf16)a.y; h[2] = (bf16)a.z; h[3] = (bf16)a.w;
  h[4] = (bf16)b.x; h[5] = (bf16)b.y; h[6] = (bf16)b.z; h[7] = (bf16)b.w;
  *(bf16x8*)(dst + base) = h;
}

// ---------------------------------------------------------------------------
// Q/K projection GEMM: 128x128 tile, BK=64, all-bf16, dbuf + counted vmcnt.
// (validated rounds 1/2/6/7/9/11/12). q epilogue scale = 0.125*log2(e) in
// fp32 BEFORE the single bf16 rounding — same one-rounding budget as 0.125.
// ---------------------------------------------------------------------------
__global__ __launch_bounds__(256) void proj_qk_kernel(
    const bf16* __restrict__ xqb, const bf16* __restrict__ xkb,
    const bf16* __restrict__ wqb, const bf16* __restrict__ wkb,
    const float* __restrict__ bqp, const float* __restrict__ bkp,
    bf16* __restrict__ qb, bf16* __restrict__ kb)
{
  const int bid = blockIdx.x;
  const int xcd = bid & 7;
  const int slot = bid >> 3;            // 0..63
  const int m_blk = xcd * 4 + (slot & 3);
  const int n_blk = (slot >> 2) & 7;
  const int z = slot >> 5;              // 0 -> q, 1 -> k

  const bf16* X     = z ? xkb : xqb;
  const bf16* W     = z ? wkb : wqb;
  const float* bias = z ? bkp : bqp;

  const int m0 = m_blk * 128;
  const int n0 = n_blk * 128;
  const int tid = threadIdx.x;
  const int lane = tid & 63;
  const int wid = tid >> 6;
  const int wm = (wid & 1) * 64;
  const int wn = (wid >> 1) * 64;

  __shared__ bf16 As[2][128 * 64];   // 2 x 16KB
  __shared__ bf16 Bs[2][128 * 64];   // 2 x 16KB

  floatx4 acc[4][4];
  #pragma unroll
  for (int i = 0; i < 4; i++)
    #pragma unroll
    for (int j = 0; j < 4; j++) acc[i][j] = (floatx4){0.f, 0.f, 0.f, 0.f};

  const int mr = lane & 15;
  const int q4 = lane >> 4;
  const int r8_in = lane >> 3, cb8_ph = lane & 7;

  // stage one K-step (32KB: A 16KB + B 16KB; 8 gll16/thread)
  #define STAGE_QK(buf, kt)                                                   \
    {                                                                         \
      _Pragma("unroll")                                                       \
      for (int j = 0; j < 4; j++) {                                           \
        const int c = wid * 4 + j;                                            \
        const int row = c * 8 + r8_in;                                        \
        const int cb = cb8_ph ^ (row & 7);                                    \
        gll16(X + (size_t)(m0 + row) * DM + (kt) + cb * 8, &As[buf][c * 512]);\
      }                                                                       \
      _Pragma("unroll")                                                       \
      for (int j = 0; j < 4; j++) {                                           \
        const int c = wid * 4 + j;                                            \
        const int row = c * 8 + r8_in;                                        \
        const int cb = cb8_ph ^ (row & 7);                                    \
        gll16(W + (size_t)(n0 + row) * DM + (kt) + cb * 8, &Bs[buf][c * 512]);\
      }                                                                       \
    }

  STAGE_QK(0, 0);
  int cur = 0;
  for (int kt = 0; kt < DM; kt += 64) {
    if (kt + 64 < DM) {
      STAGE_QK(cur ^ 1, kt + 64);
      asm volatile("s_waitcnt vmcnt(8)" ::: "memory");   // buf[cur]'s 8 landed
    } else {
      asm volatile("s_waitcnt vmcnt(0)" ::: "memory");
    }
    __builtin_amdgcn_s_barrier();   // buf[cur] visible to all waves

    #pragma unroll
    for (int kk = 0; kk < 2; kk++) {
      bf16x8 af[4], bfr[4];
      #pragma unroll
      for (int mt = 0; mt < 4; mt++) {
        const int row = wm + mt * 16 + mr;
        const int cb = 4 * kk + q4;
        af[mt] = *(const bf16x8*)&As[cur][row * 64 + (cb ^ (row & 7)) * 8];
      }
      #pragma unroll
      for (int nt = 0; nt < 4; nt++) {
        const int row = wn + nt * 16 + mr;
        const int cb = 4 * kk + q4;
        bfr[nt] = *(const bf16x8*)&Bs[cur][row * 64 + (cb ^ (row & 7)) * 8];
      }
      #pragma unroll
      for (int mt = 0; mt < 4; mt++)
        #pragma unroll
        for (int nt = 0; nt < 4; nt++)
          acc[mt][nt] = __builtin_amdgcn_mfma_f32_16x16x32_bf16(af[mt], bfr[nt], acc[mt][nt], 0, 0, 0);
    }

    __builtin_amdgcn_s_barrier();   // all reads of buf[cur] done (WAR close)
    cur ^= 1;
  }
  #undef STAGE_QK

  // q: fold 1/sqrt(Dk)*log2(e) (fp32, single bf16 rounding as before).
  const float qscale = (z == 0) ? 0.18033688011112042f : 1.0f;
  bf16* dst = (z == 0) ? qb : kb;
  #pragma unroll
  for (int nt = 0; nt < 4; nt++) {
    const int gn = n0 + wn + nt * 16 + mr;
    const float bv = bias[gn];
    const int h = gn >> 6, d = gn & 63;
    #pragma unroll
    for (int mt = 0; mt < 4; mt++) {
      const int mbase = m0 + wm + mt * 16 + q4 * 4;
      #pragma unroll
      for (int r = 0; r < 4; r++) {
        const int gm = mbase + r;
        const int bi = gm >> 11, s = gm & 2047;
        const bf16 hv = (bf16)((acc[mt][nt][r] + bv) * qscale);
        dst[(((size_t)(bi * NH + h)) * S_LEN + s) * DK + d] = hv;
      }
    }
  }
}

// ---------------------------------------------------------------------------
// V projection GEMM: A = Xv fp32 (staged raw), B = wvb bf16. dbuf, vmcnt(12).
// (validated rounds 1/2/6/7/9/11/12)
// ---------------------------------------------------------------------------
__global__ __launch_bounds__(256) void proj_v_kernel(
    const float* __restrict__ Xv, const bf16* __restrict__ wvb,
    const float* __restrict__ bvp, bf16* __restrict__ vtb)
{
  const int bid = blockIdx.x;
  const int xcd = bid & 7;
  const int slot = bid >> 3;            // 0..31
  const int m_blk = xcd * 4 + (slot & 3);
  const int n_blk = slot >> 2;          // 0..7

  const int m0 = m_blk * 128;
  const int n0 = n_blk * 128;
  const int tid = threadIdx.x;
  const int lane = tid & 63;
  const int wid = tid >> 6;
  const int wm = (wid & 1) * 64;
  const int wn = (wid >> 1) * 64;

  __shared__ float Asf[2][128 * 64];   // 2 x 32KB
  __shared__ bf16  Bs[2][128 * 64];    // 2 x 16KB

  floatx4 acc[4][4];
  #pragma unroll
  for (int i = 0; i < 4; i++)
    #pragma unroll
    for (int j = 0; j < 4; j++) acc[i][j] = (floatx4){0.f, 0.f, 0.f, 0.f};

  const int mr = lane & 15;
  const int q4 = lane >> 4;
  const int r8_in = lane >> 3, cb8_ph = lane & 7;
  const int r4_in = lane >> 4, cb16_ph = lane & 15;

  #define STAGE_V(buf, kt)                                                     \
    {                                                                          \
      _Pragma("unroll")                                                        \
      for (int j = 0; j < 8; j++) {                                            \
        const int c = wid * 8 + j;                                             \
        const int row = c * 4 + r4_in;                                         \
        const int cb = cb16_ph ^ (row & 7);                                    \
        gll16(Xv + (size_t)(m0 + row) * DM + (kt) + cb * 4, &Asf[buf][c * 256]);\
      }                                                                        \
      _Pragma("unroll")                                                        \
      for (int j = 0; j < 4; j++) {                                            \
        const int c = wid * 4 + j;                                             \
        const int row = c * 8 + r8_in;                                         \
        const int cb = cb8_ph ^ (row & 7);                                     \
        gll16(wvb + (size_t)(n0 + row) * DM + (kt) + cb * 8, &Bs[buf][c * 512]);\
      }                                                                        \
    }

  STAGE_V(0, 0);
  int cur = 0;
  for (int kt = 0; kt < DM; kt += 64) {
    if (kt + 64 < DM) {
      STAGE_V(cur ^ 1, kt + 64);
      asm volatile("s_waitcnt vmcnt(12)" ::: "memory");  // buf[cur]'s 12 landed
    } else {
      asm volatile("s_waitcnt vmcnt(0)" ::: "memory");
    }
    __builtin_amdgcn_s_barrier();

    #pragma unroll
    for (int kk = 0; kk < 2; kk++) {
      bf16x8 af[4], bfr[4];
      #pragma unroll
      for (int mt = 0; mt < 4; mt++) {
        const int row = wm + mt * 16 + mr;
        const int cb0 = 8 * kk + 2 * q4;
        const float4 lo = *(const float4*)&Asf[cur][row * 64 + (cb0 ^ (row & 7)) * 4];
        const float4 hi = *(const float4*)&Asf[cur][row * 64 + ((cb0 + 1) ^ (row & 7)) * 4];
        bf16x8 a;
        a[0] = (bf16)lo.x; a[1] = (bf16)lo.y; a[2] = (bf16)lo.z; a[3] = (bf16)lo.w;
        a[4] = (bf16)hi.x; a[5] = (bf16)hi.y; a[6] = (bf16)hi.z; a[7] = (bf16)hi.w;
        af[mt] = a;
      }
      #pragma unroll
      for (int nt = 0; nt < 4; nt++) {
        const int row = wn + nt * 16 + mr;
        const int cb = 4 * kk + q4;
        bfr[nt] = *(const bf16x8*)&Bs[cur][row * 64 + (cb ^ (row & 7)) * 8];
      }
      #pragma unroll
      for (int mt = 0; mt < 4; mt++)
        #pragma unroll
        for (int nt = 0; nt < 4; nt++)
          acc[mt][nt] = __builtin_amdgcn_mfma_f32_16x16x32_bf16(af[mt], bfr[nt], acc[mt][nt], 0, 0, 0);
    }

    __builtin_amdgcn_s_barrier();
    cur ^= 1;
  }
  #undef STAGE_V

  #pragma unroll
  for (int nt = 0; nt < 4; nt++) {
    const int gn = n0 + wn + nt * 16 + mr;
    const float bv = bvp[gn];
    const int h = gn >> 6, d = gn & 63;
    #pragma unroll
    for (int mt = 0; mt < 4; mt++) {
      const int mbase = m0 + wm + mt * 16 + q4 * 4;
      #pragma unroll
      for (int r = 0; r < 4; r++) {
        const int gm = mbase + r;
        const int bi = gm >> 11, s = gm & 2047;
        vtb[(((size_t)(bi * NH + h)) * DK + d) * S_LEN + s] = (bf16)(acc[mt][nt][r] + bv);
      }
    }
  }
}

// ---------------------------------------------------------------------------
// Flash attention, no-max softmax, q-tile 128 (wave owns 32 q-rows).
// EXACT r9 structure (best: 66-67us) with ONE change: __expf -> 2^x
// (log2e folded into q in fp32 upstream; saves 64 v_mul/iter/thread).
// ---------------------------------------------------------------------------
__global__ __launch_bounds__(256) void attn_kernel(
    const bf16* __restrict__ qb, const bf16* __restrict__ kb,
    const bf16* __restrict__ vtb, bf16* __restrict__ ob)
{
  const int bid = blockIdx.x;
  const int xcd = bid & 7;
  const int slot = bid >> 3;          // 0..63
  const int bh = xcd * 4 + (slot & 3);
  const int qt = slot >> 2;           // 0..15

  const int tid = threadIdx.x;
  const int lane = tid & 63;
  const int wid = tid >> 6;

  const bf16* qh = qb + (size_t)bh * S_LEN * DK;
  const bf16* kh = kb + (size_t)bh * S_LEN * DK;
  const bf16* vh = vtb + (size_t)bh * DK * S_LEN;

  __shared__ bf16 Ks[2][128 * 64];   // 2 x 16KB [key][8 cb], phys cb=cb^(row&7)
  __shared__ bf16 Vs[2][64 * 128];   // 2 x 16KB [d][16 cb],  phys cb=cb^(row&7)
  __shared__ bf16 Psc[4][32][40];    // per-wave 32-col P chunk (80B rows)

  const int mr = lane & 15;
  const int q4 = lane >> 4;

  bf16x8 aq[2][2];
  #pragma unroll
  for (int mt = 0; mt < 2; mt++)
    #pragma unroll
    for (int kk = 0; kk < 2; kk++)
      aq[mt][kk] = *(const bf16x8*)(qh + (size_t)(qt * 128 + wid * 32 + mt * 16 + mr) * DK + kk * 32 + q4 * 8);

  floatx4 acc_o[2][4];
  #pragma unroll
  for (int mt = 0; mt < 2; mt++)
    #pragma unroll
    for (int dt = 0; dt < 4; dt++) acc_o[mt][dt] = (floatx4){0.f, 0.f, 0.f, 0.f};
  float l_p[2][4] = {{0.f,0.f,0.f,0.f},{0.f,0.f,0.f,0.f}};

  const int r8_in = lane >> 3, cb8_ph = lane & 7;
  const int r4_in = lane >> 4, cb16_ph = lane & 15;

  #define STAGE_A(buf, s0)                                                    \
    {                                                                         \
      _Pragma("unroll")                                                       \
      for (int j = 0; j < 4; j++) {                                           \
        const int c = wid * 4 + j;                                            \
        const int row = c * 8 + r8_in;                                        \
        const int cb = cb8_ph ^ (row & 7);                                    \
        gll16(kh + (size_t)((s0) + row) * DK + cb * 8, &Ks[buf][c * 512]);    \
      }                                                                       \
      _Pragma("unroll")                                                       \
      for (int j = 0; j < 4; j++) {                                           \
        const int c = wid * 4 + j;                                            \
        const int row = c * 4 + r4_in;                                        \
        const int cb = cb16_ph ^ (row & 7);                                   \
        gll16(vh + (size_t)row * S_LEN + (s0) + cb * 8, &Vs[buf][c * 512]);   \
      }                                                                       \
    }

  STAGE_A(0, 0);
  int cur = 0;
  for (int it = 0; it < S_LEN / 128; it++) {
    if (it + 1 < S_LEN / 128) {
      STAGE_A(cur ^ 1, (it + 1) * 128);
      asm volatile("s_waitcnt vmcnt(8)" ::: "memory");   // buf[cur]'s 8 landed
    } else {
      asm volatile("s_waitcnt vmcnt(0)" ::: "memory");
    }
    __builtin_amdgcn_s_barrier();   // buf[cur] visible to all waves

    // QK^T
    floatx4 sc[2][8];
    #pragma unroll
    for (int mt = 0; mt < 2; mt++)
      #pragma unroll
      for (int i = 0; i < 8; i++) sc[mt][i] = (floatx4){0.f, 0.f, 0.f, 0.f};
    __builtin_amdgcn_s_setprio(1);
    #pragma unroll
    for (int kk = 0; kk < 2; kk++) {
      #pragma unroll
      for (int nt = 0; nt < 8; nt++) {
        const int row = nt * 16 + mr;
        const int cb = kk * 4 + q4;
        bf16x8 b = *(const bf16x8*)&Ks[cur][row * 64 + (cb ^ (row & 7)) * 8];
        #pragma unroll
        for (int mt = 0; mt < 2; mt++)
          sc[mt][nt] = __builtin_amdgcn_mfma_f32_16x16x32_bf16(aq[mt][kk], b, sc[mt][nt], 0, 0, 0);
      }
    }
    __builtin_amdgcn_s_setprio(0);

    // chunked softmax -> PV: one 32-col P chunk per kk2 (per-wave private)
    #pragma unroll
    for (int kk2 = 0; kk2 < 4; kk2++) {
      #pragma unroll
      for (int mt = 0; mt < 2; mt++)
        #pragma unroll
        for (int nt2 = 0; nt2 < 2; nt2++)
          #pragma unroll
          for (int r = 0; r < 4; r++) {
            const float pv = exp2_fast(sc[mt][kk2 * 2 + nt2][r]);  // q pre-scaled
            l_p[mt][r] += pv;
            Psc[wid][mt * 16 + q4 * 4 + r][nt2 * 16 + mr] = (bf16)pv;
          }
      bf16x8 ap[2];
      #pragma unroll
      for (int mt = 0; mt < 2; mt++)
        ap[mt] = *(const bf16x8*)&Psc[wid][mt * 16 + mr][q4 * 8];
      __builtin_amdgcn_s_setprio(1);
      #pragma unroll
      for (int dt = 0; dt < 4; dt++) {
        const int row = dt * 16 + mr;
        const int cb = kk2 * 4 + q4;
        bf16x8 b = *(const bf16x8*)&Vs[cur][row * 128 + (cb ^ (row & 7)) * 8];
        #pragma unroll
        for (int mt = 0; mt < 2; mt++)
          acc_o[mt][dt] = __builtin_amdgcn_mfma_f32_16x16x32_bf16(ap[mt], b, acc_o[mt][dt], 0, 0, 0);
      }
      __builtin_amdgcn_s_setprio(0);
    }

    __builtin_amdgcn_s_barrier();   // all reads of buf[cur] done (WAR close)
    cur ^= 1;
  }
  #undef STAGE_A

  const int bi = bh >> 4, h = bh & 15;
  #pragma unroll
  for (int mt = 0; mt < 2; mt++) {
    float inv[4];
    #pragma unroll
    for (int r = 0; r < 4; r++) {
      float v = l_p[mt][r];
      #pragma unroll
      for (int off = 1; off < 16; off <<= 1) v += __shfl_xor(v, off, 16);
      inv[r] = 1.0f / v;
    }
    #pragma unroll
    for (int dt = 0; dt < 4; dt++) {
      const int d = dt * 16 + mr;
      #pragma unroll
      for (int r = 0; r < 4; r++) {
        const int s = qt * 128 + wid * 32 + mt * 16 + q4 * 4 + r;
        ob[((size_t)(bi * S_LEN + s)) * DM + h * DK + d] = (bf16)(acc_o[mt][dt][r] * inv[r]);
      }
    }
  }
}

// ---------------------------------------------------------------------------
// Output projection: out[m,n] = sum_k AO[m,k]*Wo[n,k] + bo[n], fp32 out.
// 128x64 tile, BK=64. dbuf + counted vmcnt (validated rounds 6/7/9/12).
// ---------------------------------------------------------------------------
__global__ __launch_bounds__(256) void oproj_kernel(
    const bf16* __restrict__ X, const float* __restrict__ W,
    const float* __restrict__ bias, float* __restrict__ out)
{
  const int bid = blockIdx.x;
  const int xcd = bid & 7;
  const int slot = bid >> 3;              // 0..63
  const int m0 = (xcd * 4 + (slot & 3)) * 128;
  const int n0 = (slot >> 2) * 64;        // 0..15 -> n0

  const int tid = threadIdx.x;
  const int lane = tid & 63;
  const int wid = tid >> 6;
  const int wm = wid * 32;

  __shared__ bf16  As[2][128 * 64];   // 2 x 16KB
  __shared__ float Bsf[2][64 * 64];   // 2 x 16KB

  floatx4 acc[2][4];
  #pragma unroll
  for (int i = 0; i < 2; i++)
    #pragma unroll
    for (int j = 0; j < 4; j++) acc[i][j] = (floatx4){0.f, 0.f, 0.f, 0.f};

  const int mr = lane & 15;
  const int q4 = lane >> 4;

  const int r8_in = lane >> 3, cb8_ph = lane & 7;
  const int r4_in = lane >> 4, cb16_ph = lane & 15;

  #define STAGE_O(buf, kt)                                                    \
    {                                                                         \
      _Pragma("unroll")                                                       \
      for (int j = 0; j < 4; j++) {                                           \
        const int c = wid * 4 + j;                                            \
        const int row = c * 8 + r8_in;                                        \
        const int cb = cb8_ph ^ (row & 7);                                    \
        gll16(X + (size_t)(m0 + row) * DM + (kt) + cb * 8, &As[buf][c * 512]);\
      }                                                                       \
      _Pragma("unroll")                                                       \
      for (int j = 0; j < 4; j++) {                                           \
        const int c = wid * 4 + j;                                            \
        const int row = c * 4 + r4_in;                                        \
        const int cb = cb16_ph ^ (row & 7);                                   \
        gll16(W + (size_t)(n0 + row) * DM + (kt) + cb * 4, &Bsf[buf][c * 256]);\
      }                                                                       \
    }

  STAGE_O(0, 0);
  int cur = 0;
  for (int kt = 0; kt < DM; kt += 64) {
    if (kt + 64 < DM) {
      STAGE_O(cur ^ 1, kt + 64);
      asm volatile("s_waitcnt vmcnt(8)" ::: "memory");   // buf[cur]'s 8 landed
    } else {
      asm volatile("s_waitcnt vmcnt(0)" ::: "memory");
    }
    __builtin_amdgcn_s_barrier();

    #pragma unroll
    for (int kk = 0; kk < 2; kk++) {
      bf16x8 af[2], bfr[4];
      #pragma unroll
      for (int mt = 0; mt < 2; mt++) {
        const int row = wm + mt * 16 + mr;
        const int cb = 4 * kk + q4;
        af[mt] = *(const bf16x8*)&As[cur][row * 64 + (cb ^ (row & 7)) * 8];
      }
      #pragma unroll
      for (int nt = 0; nt < 4; nt++) {
        const int row = nt * 16 + mr;
        const int cb0 = 8 * kk + 2 * q4;
        const float4 lo = *(const float4*)&Bsf[cur][row * 64 + (cb0 ^ (row & 7)) * 4];
        const float4 hi = *(const float4*)&Bsf[cur][row * 64 + ((cb0 + 1) ^ (row & 7)) * 4];
        bf16x8 b;
        b[0] = (bf16)lo.x; b[1] = (bf16)lo.y; b[2] = (bf16)lo.z; b[3] = (bf16)lo.w;
        b[4] = (bf16)hi.x; b[5] = (bf16)hi.y; b[6] = (bf16)hi.z; b[7] = (bf16)hi.w;
        bfr[nt] = b;
      }
      #pragma unroll
      for (int mt = 0; mt < 2; mt++)
        #pragma unroll
        for (int nt = 0; nt < 4; nt++)
          acc[mt][nt] = __builtin_amdgcn_mfma_f32_16x16x32_bf16(af[mt], bfr[nt], acc[mt][nt], 0, 0, 0);
    }

    __builtin_amdgcn_s_barrier();
    cur ^= 1;
  }
  #undef STAGE_O

  #pragma unroll
  for (int nt = 0; nt < 4; nt++) {
    const int gn = n0 + nt * 16 + mr;
    const float bv = bias[gn];
    #pragma unroll
    for (int mt = 0; mt < 2; mt++) {
      const int mbase = m0 + wm + mt * 16 + q4 * 4;
      #pragma unroll
      for (int r = 0; r < 4; r++)
        out[(size_t)(mbase + r) * DM + gn] = acc[mt][nt][r] + bv;
    }
  }
}

// ---------------------------------------------------------------------------
extern "C" void kernel_launch(void* const* d_in, const int* in_sizes, int n_in,
                              void* d_out, int out_size, void* d_ws, size_t ws_size,
                              hipStream_t stream) {
  const float* Q  = (const float*)d_in[0];
  const float* K  = (const float*)d_in[1];
  const float* V  = (const float*)d_in[2];
  const float* Wq = (const float*)d_in[3];
  const float* bq = (const float*)d_in[4];
  const float* Wk = (const float*)d_in[5];
  const float* bk = (const float*)d_in[6];
  const float* Wv = (const float*)d_in[7];
  const float* bv = (const float*)d_in[8];
  const float* Wo = (const float*)d_in[9];
  const float* bo = (const float*)d_in[10];
  float* out = (float*)d_out;

  const size_t NE = (size_t)MTOT * DM;      // 4 Mi elems
  bf16* qb  = (bf16*)d_ws;                  // [B,H,S,Dk] (q pre-scaled)
  bf16* kb  = qb + NE;
  bf16* vtb = kb + NE;                      // [B,H,Dk,S]
  bf16* ao  = vtb + NE;                     // [B*S, DM] attn out
  // bf16 weights aliased into ao (live only during proj; attn overwrites ao).
  bf16* wqb = ao;
  bf16* wkb = ao + (size_t)DM * DM;
  bf16* wvb = ao + 2 * (size_t)DM * DM;
  // bf16 Xq/Xk staged in d_out (dead until oproj writes the real output).
  bf16* xqb = (bf16*)d_out;
  bf16* xkb = xqb + NE;

  cvt_kernel<<<dim3(5632), 256, 0, stream>>>(Wq, Wk, Wv, Q, K, wqb, wkb, wvb, xqb, xkb);
  proj_qk_kernel<<<dim3(512), 256, 0, stream>>>(xqb, xkb, wqb, wkb, bq, bk, qb, kb);
  proj_v_kernel<<<dim3(256), 256, 0, stream>>>(V, wvb, bv, vtb);
  attn_kernel<<<dim3(512), 256, 0, stream>>>(qb, kb, vtb, ao);
  oproj_kernel<<<dim3(512), 256, 0, stream>>>(ao, Wo, bo, out);
}

// Round 15
// 243.707 us; speedup vs baseline: 1.0218x; 1.0035x over previous
//
#include <hip/hip_runtime.h>
#include <stdint.h>

typedef __bf16 bf16;
typedef __bf16 bf16x8 __attribute__((ext_vector_type(8)));
typedef float floatx4 __attribute__((ext_vector_type(4)));

#define S_LEN 2048
#define DM 1024
#define NH 16
#define DK 64
#define MTOT 4096  // B*S

// async 16B/lane global->LDS DMA; lane l's 16B lands at ldsbase + l*16.
__device__ __forceinline__ void gll16(const void* g, void* l) {
  __builtin_amdgcn_global_load_lds(
      (const __attribute__((address_space(1))) void*)g,
      (__attribute__((address_space(3))) void*)l, 16, 0, 0);
}

// 2^x via the native transcendental (log2e folded into q upstream, in fp32).
__device__ __forceinline__ float exp2_fast(float x) {
  float r; asm("v_exp_f32 %0, %1" : "=v"(r) : "v"(x)); return r;
}

// ---------------------------------------------------------------------------
// fp32 -> bf16 convert: Wq,Wk,Wv (512 chunks each) + Xq,Xk (2048 chunks each).
// ---------------------------------------------------------------------------
__global__ __launch_bounds__(256) void cvt_kernel(
    const float* __restrict__ Wq, const float* __restrict__ Wk, const float* __restrict__ Wv,
    const float* __restrict__ Xq, const float* __restrict__ Xk,
    bf16* __restrict__ wqb, bf16* __restrict__ wkb, bf16* __restrict__ wvb,
    bf16* __restrict__ xqb, bf16* __restrict__ xkb)
{
  const int c = blockIdx.x;
  const float* src; bf16* dst; int off;
  if      (c < 512)  { src = Wq; dst = wqb; off = c; }
  else if (c < 1024) { src = Wk; dst = wkb; off = c - 512; }
  else if (c < 1536) { src = Wv; dst = wvb; off = c - 1024; }
  else if (c < 3584) { src = Xq; dst = xqb; off = c - 1536; }
  else               { src = Xk; dst = xkb; off = c - 3584; }
  const size_t base = (size_t)off * 2048 + threadIdx.x * 8;
  float4 a = *(const float4*)(src + base);
  float4 b = *(const float4*)(src + base + 4);
  bf16x8 h;
  h[0] = (bf16)a.x; h[1] = (bf16)a.y; h[2] = (bf16)a.z; h[3] = (bf16)a.w;
  h[4] = (bf16)b.x; h[5] = (bf16)b.y; h[6] = (bf16)b.z; h[7] = (bf16)b.w;
  *(bf16x8*)(dst + base) = h;
}

// ---------------------------------------------------------------------------
// Q/K projection GEMM: 128x128 tile, BK=64, all-bf16, dbuf + counted vmcnt.
// (validated rounds 1/2/6/7/9/11/12/13). q scale = 0.125*log2(e) in fp32.
// ---------------------------------------------------------------------------
__global__ __launch_bounds__(256) void proj_qk_kernel(
    const bf16* __restrict__ xqb, const bf16* __restrict__ xkb,
    const bf16* __restrict__ wqb, const bf16* __restrict__ wkb,
    const float* __restrict__ bqp, const float* __restrict__ bkp,
    bf16* __restrict__ qb, bf16* __restrict__ kb)
{
  const int bid = blockIdx.x;
  const int xcd = bid & 7;
  const int slot = bid >> 3;            // 0..63
  const int m_blk = xcd * 4 + (slot & 3);
  const int n_blk = (slot >> 2) & 7;
  const int z = slot >> 5;              // 0 -> q, 1 -> k

  const bf16* X     = z ? xkb : xqb;
  const bf16* W     = z ? wkb : wqb;
  const float* bias = z ? bkp : bqp;

  const int m0 = m_blk * 128;
  const int n0 = n_blk * 128;
  const int tid = threadIdx.x;
  const int lane = tid & 63;
  const int wid = tid >> 6;
  const int wm = (wid & 1) * 64;
  const int wn = (wid >> 1) * 64;

  __shared__ bf16 As[2][128 * 64];   // 2 x 16KB
  __shared__ bf16 Bs[2][128 * 64];   // 2 x 16KB

  floatx4 acc[4][4];
  #pragma unroll
  for (int i = 0; i < 4; i++)
    #pragma unroll
    for (int j = 0; j < 4; j++) acc[i][j] = (floatx4){0.f, 0.f, 0.f, 0.f};

  const int mr = lane & 15;
  const int q4 = lane >> 4;
  const int r8_in = lane >> 3, cb8_ph = lane & 7;

  // stage one K-step (32KB: A 16KB + B 16KB; 8 gll16/thread)
  #define STAGE_QK(buf, kt)                                                   \
    {                                                                         \
      _Pragma("unroll")                                                       \
      for (int j = 0; j < 4; j++) {                                           \
        const int c = wid * 4 + j;                                            \
        const int row = c * 8 + r8_in;                                        \
        const int cb = cb8_ph ^ (row & 7);                                    \
        gll16(X + (size_t)(m0 + row) * DM + (kt) + cb * 8, &As[buf][c * 512]);\
      }                                                                       \
      _Pragma("unroll")                                                       \
      for (int j = 0; j < 4; j++) {                                           \
        const int c = wid * 4 + j;                                            \
        const int row = c * 8 + r8_in;                                        \
        const int cb = cb8_ph ^ (row & 7);                                    \
        gll16(W + (size_t)(n0 + row) * DM + (kt) + cb * 8, &Bs[buf][c * 512]);\
      }                                                                       \
    }

  STAGE_QK(0, 0);
  int cur = 0;
  for (int kt = 0; kt < DM; kt += 64) {
    if (kt + 64 < DM) {
      STAGE_QK(cur ^ 1, kt + 64);
      asm volatile("s_waitcnt vmcnt(8)" ::: "memory");   // buf[cur]'s 8 landed
    } else {
      asm volatile("s_waitcnt vmcnt(0)" ::: "memory");
    }
    __builtin_amdgcn_s_barrier();   // buf[cur] visible to all waves

    #pragma unroll
    for (int kk = 0; kk < 2; kk++) {
      bf16x8 af[4], bfr[4];
      #pragma unroll
      for (int mt = 0; mt < 4; mt++) {
        const int row = wm + mt * 16 + mr;
        const int cb = 4 * kk + q4;
        af[mt] = *(const bf16x8*)&As[cur][row * 64 + (cb ^ (row & 7)) * 8];
      }
      #pragma unroll
      for (int nt = 0; nt < 4; nt++) {
        const int row = wn + nt * 16 + mr;
        const int cb = 4 * kk + q4;
        bfr[nt] = *(const bf16x8*)&Bs[cur][row * 64 + (cb ^ (row & 7)) * 8];
      }
      #pragma unroll
      for (int mt = 0; mt < 4; mt++)
        #pragma unroll
        for (int nt = 0; nt < 4; nt++)
          acc[mt][nt] = __builtin_amdgcn_mfma_f32_16x16x32_bf16(af[mt], bfr[nt], acc[mt][nt], 0, 0, 0);
    }

    __builtin_amdgcn_s_barrier();   // all reads of buf[cur] done (WAR close)
    cur ^= 1;
  }
  #undef STAGE_QK

  // q: fold 1/sqrt(Dk)*log2(e) (fp32, single bf16 rounding as before).
  const float qscale = (z == 0) ? 0.18033688011112042f : 1.0f;
  bf16* dst = (z == 0) ? qb : kb;
  #pragma unroll
  for (int nt = 0; nt < 4; nt++) {
    const int gn = n0 + wn + nt * 16 + mr;
    const float bv = bias[gn];
    const int h = gn >> 6, d = gn & 63;
    #pragma unroll
    for (int mt = 0; mt < 4; mt++) {
      const int mbase = m0 + wm + mt * 16 + q4 * 4;
      #pragma unroll
      for (int r = 0; r < 4; r++) {
        const int gm = mbase + r;
        const int bi = gm >> 11, s = gm & 2047;
        const bf16 hv = (bf16)((acc[mt][nt][r] + bv) * qscale);
        dst[(((size_t)(bi * NH + h)) * S_LEN + s) * DK + d] = hv;
      }
    }
  }
}

// ---------------------------------------------------------------------------
// V projection GEMM: A = Xv fp32 (staged raw), B = wvb bf16. dbuf, vmcnt(12).
// (validated rounds 1/2/6/7/9/11/12/13)
// ---------------------------------------------------------------------------
__global__ __launch_bounds__(256) void proj_v_kernel(
    const float* __restrict__ Xv, const bf16* __restrict__ wvb,
    const float* __restrict__ bvp, bf16* __restrict__ vtb)
{
  const int bid = blockIdx.x;
  const int xcd = bid & 7;
  const int slot = bid >> 3;            // 0..31
  const int m_blk = xcd * 4 + (slot & 3);
  const int n_blk = slot >> 2;          // 0..7

  const int m0 = m_blk * 128;
  const int n0 = n_blk * 128;
  const int tid = threadIdx.x;
  const int lane = tid & 63;
  const int wid = tid >> 6;
  const int wm = (wid & 1) * 64;
  const int wn = (wid >> 1) * 64;

  __shared__ float Asf[2][128 * 64];   // 2 x 32KB
  __shared__ bf16  Bs[2][128 * 64];    // 2 x 16KB

  floatx4 acc[4][4];
  #pragma unroll
  for (int i = 0; i < 4; i++)
    #pragma unroll
    for (int j = 0; j < 4; j++) acc[i][j] = (floatx4){0.f, 0.f, 0.f, 0.f};

  const int mr = lane & 15;
  const int q4 = lane >> 4;
  const int r8_in = lane >> 3, cb8_ph = lane & 7;
  const int r4_in = lane >> 4, cb16_ph = lane & 15;

  #define STAGE_V(buf, kt)                                                     \
    {                                                                          \
      _Pragma("unroll")                                                        \
      for (int j = 0; j < 8; j++) {                                            \
        const int c = wid * 8 + j;                                             \
        const int row = c * 4 + r4_in;                                         \
        const int cb = cb16_ph ^ (row & 7);                                    \
        gll16(Xv + (size_t)(m0 + row) * DM + (kt) + cb * 4, &Asf[buf][c * 256]);\
      }                                                                        \
      _Pragma("unroll")                                                        \
      for (int j = 0; j < 4; j++) {                                            \
        const int c = wid * 4 + j;                                             \
        const int row = c * 8 + r8_in;                                         \
        const int cb = cb8_ph ^ (row & 7);                                     \
        gll16(wvb + (size_t)(n0 + row) * DM + (kt) + cb * 8, &Bs[buf][c * 512]);\
      }                                                                        \
    }

  STAGE_V(0, 0);
  int cur = 0;
  for (int kt = 0; kt < DM; kt += 64) {
    if (kt + 64 < DM) {
      STAGE_V(cur ^ 1, kt + 64);
      asm volatile("s_waitcnt vmcnt(12)" ::: "memory");  // buf[cur]'s 12 landed
    } else {
      asm volatile("s_waitcnt vmcnt(0)" ::: "memory");
    }
    __builtin_amdgcn_s_barrier();

    #pragma unroll
    for (int kk = 0; kk < 2; kk++) {
      bf16x8 af[4], bfr[4];
      #pragma unroll
      for (int mt = 0; mt < 4; mt++) {
        const int row = wm + mt * 16 + mr;
        const int cb0 = 8 * kk + 2 * q4;
        const float4 lo = *(const float4*)&Asf[cur][row * 64 + (cb0 ^ (row & 7)) * 4];
        const float4 hi = *(const float4*)&Asf[cur][row * 64 + ((cb0 + 1) ^ (row & 7)) * 4];
        bf16x8 a;
        a[0] = (bf16)lo.x; a[1] = (bf16)lo.y; a[2] = (bf16)lo.z; a[3] = (bf16)lo.w;
        a[4] = (bf16)hi.x; a[5] = (bf16)hi.y; a[6] = (bf16)hi.z; a[7] = (bf16)hi.w;
        af[mt] = a;
      }
      #pragma unroll
      for (int nt = 0; nt < 4; nt++) {
        const int row = wn + nt * 16 + mr;
        const int cb = 4 * kk + q4;
        bfr[nt] = *(const bf16x8*)&Bs[cur][row * 64 + (cb ^ (row & 7)) * 8];
      }
      #pragma unroll
      for (int mt = 0; mt < 4; mt++)
        #pragma unroll
        for (int nt = 0; nt < 4; nt++)
          acc[mt][nt] = __builtin_amdgcn_mfma_f32_16x16x32_bf16(af[mt], bfr[nt], acc[mt][nt], 0, 0, 0);
    }

    __builtin_amdgcn_s_barrier();
    cur ^= 1;
  }
  #undef STAGE_V

  #pragma unroll
  for (int nt = 0; nt < 4; nt++) {
    const int gn = n0 + wn + nt * 16 + mr;
    const float bv = bvp[gn];
    const int h = gn >> 6, d = gn & 63;
    #pragma unroll
    for (int mt = 0; mt < 4; mt++) {
      const int mbase = m0 + wm + mt * 16 + q4 * 4;
      #pragma unroll
      for (int r = 0; r < 4; r++) {
        const int gm = mbase + r;
        const int bi = gm >> 11, s = gm & 2047;
        vtb[(((size_t)(bi * NH + h)) * DK + d) * S_LEN + s] = (bf16)(acc[mt][nt][r] + bv);
      }
    }
  }
}

// ---------------------------------------------------------------------------
// Flash attention, no-max softmax, q-tile 128 (wave owns 32 q-rows).
// r13 base (63.6us) + T15 double-pipeline: QK^T split into four 32-key
// chunks; chunk c's 8 MFMA overlap chunk c-1's exp/store VALU. Race-free
// by construction: body only reads buf[cur] and writes per-wave Psc, so
// per-wave reordering preserves semantics; barriers unchanged. Named pA/pB
// (rule #20), hand-unrolled rotation.
// ---------------------------------------------------------------------------
__global__ __launch_bounds__(256) void attn_kernel(
    const bf16* __restrict__ qb, const bf16* __restrict__ kb,
    const bf16* __restrict__ vtb, bf16* __restrict__ ob)
{
  const int bid = blockIdx.x;
  const int xcd = bid & 7;
  const int slot = bid >> 3;          // 0..63
  const int bh = xcd * 4 + (slot & 3);
  const int qt = slot >> 2;           // 0..15

  const int tid = threadIdx.x;
  const int lane = tid & 63;
  const int wid = tid >> 6;

  const bf16* qh = qb + (size_t)bh * S_LEN * DK;
  const bf16* kh = kb + (size_t)bh * S_LEN * DK;
  const bf16* vh = vtb + (size_t)bh * DK * S_LEN;

  __shared__ bf16 Ks[2][128 * 64];   // 2 x 16KB [key][8 cb], phys cb=cb^(row&7)
  __shared__ bf16 Vs[2][64 * 128];   // 2 x 16KB [d][16 cb],  phys cb=cb^(row&7)
  __shared__ bf16 Psc[4][32][40];    // per-wave 32-col P chunk (80B rows)

  const int mr = lane & 15;
  const int q4 = lane >> 4;

  bf16x8 aq[2][2];
  #pragma unroll
  for (int mt = 0; mt < 2; mt++)
    #pragma unroll
    for (int kk = 0; kk < 2; kk++)
      aq[mt][kk] = *(const bf16x8*)(qh + (size_t)(qt * 128 + wid * 32 + mt * 16 + mr) * DK + kk * 32 + q4 * 8);

  floatx4 acc_o[2][4];
  #pragma unroll
  for (int mt = 0; mt < 2; mt++)
    #pragma unroll
    for (int dt = 0; dt < 4; dt++) acc_o[mt][dt] = (floatx4){0.f, 0.f, 0.f, 0.f};
  float l_p[2][4] = {{0.f,0.f,0.f,0.f},{0.f,0.f,0.f,0.f}};

  const int r8_in = lane >> 3, cb8_ph = lane & 7;
  const int r4_in = lane >> 4, cb16_ph = lane & 15;

  #define STAGE_A(buf, s0)                                                    \
    {                                                                         \
      _Pragma("unroll")                                                       \
      for (int j = 0; j < 4; j++) {                                           \
        const int c = wid * 4 + j;                                            \
        const int row = c * 8 + r8_in;                                        \
        const int cb = cb8_ph ^ (row & 7);                                    \
        gll16(kh + (size_t)((s0) + row) * DK + cb * 8, &Ks[buf][c * 512]);    \
      }                                                                       \
      _Pragma("unroll")                                                       \
      for (int j = 0; j < 4; j++) {                                           \
        const int c = wid * 4 + j;                                            \
        const int row = c * 4 + r4_in;                                        \
        const int cb = cb16_ph ^ (row & 7);                                   \
        gll16(vh + (size_t)row * S_LEN + (s0) + cb * 8, &Vs[buf][c * 512]);   \
      }                                                                       \
    }

  // QK^T for one 32-key chunk c into dst[2][2] (must be zeroed by caller).
  #define QKT(dst, c)                                                         \
    {                                                                         \
      _Pragma("unroll")                                                       \
      for (int kk = 0; kk < 2; kk++) {                                        \
        _Pragma("unroll")                                                     \
        for (int nt2 = 0; nt2 < 2; nt2++) {                                   \
          const int row = ((c) * 2 + nt2) * 16 + mr;                          \
          const int cb = kk * 4 + q4;                                         \
          bf16x8 b = *(const bf16x8*)&Ks[cur][row * 64 + (cb ^ (row & 7)) * 8];\
          _Pragma("unroll")                                                   \
          for (int mt = 0; mt < 2; mt++)                                      \
            dst[mt][nt2] = __builtin_amdgcn_mfma_f32_16x16x32_bf16(           \
                aq[mt][kk], b, dst[mt][nt2], 0, 0, 0);                        \
        }                                                                     \
      }                                                                       \
    }

  // softmax + PV for one 32-key chunk c from src[2][2].
  #define SMPV(src, c)                                                        \
    {                                                                         \
      _Pragma("unroll")                                                       \
      for (int mt = 0; mt < 2; mt++)                                          \
        _Pragma("unroll")                                                     \
        for (int nt2 = 0; nt2 < 2; nt2++)                                     \
          _Pragma("unroll")                                                   \
          for (int r = 0; r < 4; r++) {                                       \
            const float pv = exp2_fast(src[mt][nt2][r]);                      \
            l_p[mt][r] += pv;                                                 \
            Psc[wid][mt * 16 + q4 * 4 + r][nt2 * 16 + mr] = (bf16)pv;         \
          }                                                                   \
      bf16x8 ap[2];                                                           \
      _Pragma("unroll")                                                       \
      for (int mt = 0; mt < 2; mt++)                                          \
        ap[mt] = *(const bf16x8*)&Psc[wid][mt * 16 + mr][q4 * 8];             \
      __builtin_amdgcn_s_setprio(1);                                          \
      _Pragma("unroll")                                                       \
      for (int dt = 0; dt < 4; dt++) {                                        \
        const int row = dt * 16 + mr;                                         \
        const int cb = (c) * 4 + q4;                                          \
        bf16x8 b = *(const bf16x8*)&Vs[cur][row * 128 + (cb ^ (row & 7)) * 8];\
        _Pragma("unroll")                                                     \
        for (int mt = 0; mt < 2; mt++)                                        \
          acc_o[mt][dt] = __builtin_amdgcn_mfma_f32_16x16x32_bf16(            \
              ap[mt], b, acc_o[mt][dt], 0, 0, 0);                             \
      }                                                                       \
      __builtin_amdgcn_s_setprio(0);                                          \
    }

  #define ZERO22(d)                                                           \
    {                                                                         \
      _Pragma("unroll")                                                       \
      for (int mt = 0; mt < 2; mt++)                                          \
        _Pragma("unroll")                                                     \
        for (int nt2 = 0; nt2 < 2; nt2++) d[mt][nt2] = (floatx4){0.f,0.f,0.f,0.f};\
    }

  STAGE_A(0, 0);
  int cur = 0;
  for (int it = 0; it < S_LEN / 128; it++) {
    if (it + 1 < S_LEN / 128) {
      STAGE_A(cur ^ 1, (it + 1) * 128);
      asm volatile("s_waitcnt vmcnt(8)" ::: "memory");   // buf[cur]'s 8 landed
    } else {
      asm volatile("s_waitcnt vmcnt(0)" ::: "memory");
    }
    __builtin_amdgcn_s_barrier();   // buf[cur] visible to all waves

    floatx4 pA[2][2], pB[2][2];
    // prologue: chunk 0
    ZERO22(pA);
    __builtin_amdgcn_s_setprio(1);
    QKT(pA, 0);
    __builtin_amdgcn_s_setprio(0);
    // steady: QKT(c) overlaps SMPV(c-1) — independent MFMA/VALU streams
    ZERO22(pB);
    QKT(pB, 1);
    SMPV(pA, 0);
    ZERO22(pA);
    QKT(pA, 2);
    SMPV(pB, 1);
    ZERO22(pB);
    QKT(pB, 3);
    SMPV(pA, 2);
    // epilogue: chunk 3
    SMPV(pB, 3);

    __builtin_amdgcn_s_barrier();   // all reads of buf[cur] done (WAR close)
    cur ^= 1;
  }
  #undef ZERO22
  #undef SMPV
  #undef QKT
  #undef STAGE_A

  const int bi = bh >> 4, h = bh & 15;
  #pragma unroll
  for (int mt = 0; mt < 2; mt++) {
    float inv[4];
    #pragma unroll
    for (int r = 0; r < 4; r++) {
      float v = l_p[mt][r];
      #pragma unroll
      for (int off = 1; off < 16; off <<= 1) v += __shfl_xor(v, off, 16);
      inv[r] = 1.0f / v;
    }
    #pragma unroll
    for (int dt = 0; dt < 4; dt++) {
      const int d = dt * 16 + mr;
      #pragma unroll
      for (int r = 0; r < 4; r++) {
        const int s = qt * 128 + wid * 32 + mt * 16 + q4 * 4 + r;
        ob[((size_t)(bi * S_LEN + s)) * DM + h * DK + d] = (bf16)(acc_o[mt][dt][r] * inv[r]);
      }
    }
  }
}

// ---------------------------------------------------------------------------
// Output projection: out[m,n] = sum_k AO[m,k]*Wo[n,k] + bo[n], fp32 out.
// 128x64 tile, BK=64. dbuf + counted vmcnt (validated rounds 6/7/9/12/13).
// ---------------------------------------------------------------------------
__global__ __launch_bounds__(256) void oproj_kernel(
    const bf16* __restrict__ X, const float* __restrict__ W,
    const float* __restrict__ bias, float* __restrict__ out)
{
  const int bid = blockIdx.x;
  const int xcd = bid & 7;
  const int slot = bid >> 3;              // 0..63
  const int m0 = (xcd * 4 + (slot & 3)) * 128;
  const int n0 = (slot >> 2) * 64;        // 0..15 -> n0

  const int tid = threadIdx.x;
  const int lane = tid & 63;
  const int wid = tid >> 6;
  const int wm = wid * 32;

  __shared__ bf16  As[2][128 * 64];   // 2 x 16KB
  __shared__ float Bsf[2][64 * 64];   // 2 x 16KB

  floatx4 acc[2][4];
  #pragma unroll
  for (int i = 0; i < 2; i++)
    #pragma unroll
    for (int j = 0; j < 4; j++) acc[i][j] = (floatx4){0.f, 0.f, 0.f, 0.f};

  const int mr = lane & 15;
  const int q4 = lane >> 4;

  const int r8_in = lane >> 3, cb8_ph = lane & 7;
  const int r4_in = lane >> 4, cb16_ph = lane & 15;

  #define STAGE_O(buf, kt)                                                    \
    {                                                                         \
      _Pragma("unroll")                                                       \
      for (int j = 0; j < 4; j++) {                                           \
        const int c = wid * 4 + j;                                            \
        const int row = c * 8 + r8_in;                                        \
        const int cb = cb8_ph ^ (row & 7);                                    \
        gll16(X + (size_t)(m0 + row) * DM + (kt) + cb * 8, &As[buf][c * 512]);\
      }                                                                       \
      _Pragma("unroll")                                                       \
      for (int j = 0; j < 4; j++) {                                           \
        const int c = wid * 4 + j;                                            \
        const int row = c * 4 + r4_in;                                        \
        const int cb = cb16_ph ^ (row & 7);                                   \
        gll16(W + (size_t)(n0 + row) * DM + (kt) + cb * 4, &Bsf[buf][c * 256]);\
      }                                                                       \
    }

  STAGE_O(0, 0);
  int cur = 0;
  for (int kt = 0; kt < DM; kt += 64) {
    if (kt + 64 < DM) {
      STAGE_O(cur ^ 1, kt + 64);
      asm volatile("s_waitcnt vmcnt(8)" ::: "memory");   // buf[cur]'s 8 landed
    } else {
      asm volatile("s_waitcnt vmcnt(0)" ::: "memory");
    }
    __builtin_amdgcn_s_barrier();

    #pragma unroll
    for (int kk = 0; kk < 2; kk++) {
      bf16x8 af[2], bfr[4];
      #pragma unroll
      for (int mt = 0; mt < 2; mt++) {
        const int row = wm + mt * 16 + mr;
        const int cb = 4 * kk + q4;
        af[mt] = *(const bf16x8*)&As[cur][row * 64 + (cb ^ (row & 7)) * 8];
      }
      #pragma unroll
      for (int nt = 0; nt < 4; nt++) {
        const int row = nt * 16 + mr;
        const int cb0 = 8 * kk + 2 * q4;
        const float4 lo = *(const float4*)&Bsf[cur][row * 64 + (cb0 ^ (row & 7)) * 4];
        const float4 hi = *(const float4*)&Bsf[cur][row * 64 + ((cb0 + 1) ^ (row & 7)) * 4];
        bf16x8 b;
        b[0] = (bf16)lo.x; b[1] = (bf16)lo.y; b[2] = (bf16)lo.z; b[3] = (bf16)lo.w;
        b[4] = (bf16)hi.x; b[5] = (bf16)hi.y; b[6] = (bf16)hi.z; b[7] = (bf16)hi.w;
        bfr[nt] = b;
      }
      #pragma unroll
      for (int mt = 0; mt < 2; mt++)
        #pragma unroll
        for (int nt = 0; nt < 4; nt++)
          acc[mt][nt] = __builtin_amdgcn_mfma_f32_16x16x32_bf16(af[mt], bfr[nt], acc[mt][nt], 0, 0, 0);
    }

    __builtin_amdgcn_s_barrier();
    cur ^= 1;
  }
  #undef STAGE_O

  #pragma unroll
  for (int nt = 0; nt < 4; nt++) {
    const int gn = n0 + nt * 16 + mr;
    const float bv = bias[gn];
    #pragma unroll
    for (int mt = 0; mt < 2; mt++) {
      const int mbase = m0 + wm + mt * 16 + q4 * 4;
      #pragma unroll
      for (int r = 0; r < 4; r++)
        out[(size_t)(mbase + r) * DM + gn] = acc[mt][nt][r] + bv;
    }
  }
}

// ---------------------------------------------------------------------------
extern "C" void kernel_launch(void* const* d_in, const int* in_sizes, int n_in,
                              void* d_out, int out_size, void* d_ws, size_t ws_size,
                              hipStream_t stream) {
  const float* Q  = (const float*)d_in[0];
  const float* K  = (const float*)d_in[1];
  const float* V  = (const float*)d_in[2];
  const float* Wq = (const float*)d_in[3];
  const float* bq = (const float*)d_in[4];
  const float* Wk = (const float*)d_in[5];
  const float* bk = (const float*)d_in[6];
  const float* Wv = (const float*)d_in[7];
  const float* bv = (const float*)d_in[8];
  const float* Wo = (const float*)d_in[9];
  const float* bo = (const float*)d_in[10];
  float* out = (float*)d_out;

  const size_t NE = (size_t)MTOT * DM;      // 4 Mi elems
  bf16* qb  = (bf16*)d_ws;                  // [B,H,S,Dk] (q pre-scaled)
  bf16* kb  = qb + NE;
  bf16* vtb = kb + NE;                      // [B,H,Dk,S]
  bf16* ao  = vtb + NE;                     // [B*S, DM] attn out
  // bf16 weights aliased into ao (live only during proj; attn overwrites ao).
  bf16* wqb = ao;
  bf16* wkb = ao + (size_t)DM * DM;
  bf16* wvb = ao + 2 * (size_t)DM * DM;
  // bf16 Xq/Xk staged in d_out (dead until oproj writes the real output).
  bf16* xqb = (bf16*)d_out;
  bf16* xkb = xqb + NE;

  cvt_kernel<<<dim3(5632), 256, 0, stream>>>(Wq, Wk, Wv, Q, K, wqb, wkb, wvb, xqb, xkb);
  proj_qk_kernel<<<dim3(512), 256, 0, stream>>>(xqb, xkb, wqb, wkb, bq, bk, qb, kb);
  proj_v_kernel<<<dim3(256), 256, 0, stream>>>(V, wvb, bv, vtb);
  attn_kernel<<<dim3(512), 256, 0, stream>>>(qb, kb, vtb, ao);
  oproj_kernel<<<dim3(512), 256, 0, stream>>>(ao, Wo, bo, out);
}